// Round 1
// 1219.004 us; speedup vs baseline: 1.5919x; 1.5919x over previous
//
#include <hip/hip_runtime.h>

// NLCE: non-local (channel attention) + Deep-TEN encoding, B=8 C=512 C1=256 D=128 K=32 N=9216.
// All inputs/outputs fp32. Internal compute fp32 (big GEMMs on matrix cores via
// multi-limb bf16 split: G uses 3 limbs (~fp32-exact), z/zq use 2 limbs (~1.5e-5 rel)).
// Algebra: z = (W2 f Wg + I) X + q 1^T with f = softmax(Wth G Wph^T + bias terms), G = X X^T.

typedef unsigned short u16;

#define Bb 8
#define Cc 512
#define C1 256
#define Dd 128
#define Kk 32
#define Nn 9216

typedef __attribute__((ext_vector_type(8))) short short8v;
typedef __attribute__((ext_vector_type(4))) short short4v;
typedef __attribute__((ext_vector_type(4))) float f32x4;

__device__ __forceinline__ float b2f(u16 u) {
  union { unsigned int i; float f; } v; v.i = ((unsigned int)u) << 16; return v.f;
}
__device__ __forceinline__ u16 f2b(float f) {
  union { float f; unsigned int i; } v; v.f = f;
  unsigned int x = v.i;
  return (u16)((x + 0x7fffu + ((x >> 16) & 1u)) >> 16);  // RNE
}

__device__ __forceinline__ float b2fOrF(float x) { return x; }
__device__ __forceinline__ float b2fOrF(u16 x) { return b2f(x); }

__device__ __forceinline__ float4 load4(const float* p) { return *(const float4*)p; }
__device__ __forceinline__ float4 load4(const u16* p) {
  ushort4 q = *(const ushort4*)p;
  return make_float4(b2f(q.x), b2f(q.y), b2f(q.z), b2f(q.w));
}
__device__ __forceinline__ void store4(float* p, float a, float b, float c, float d) {
  *(float4*)p = make_float4(a, b, c, d);
}
__device__ __forceinline__ void store4(u16* p, float a, float b, float c, float d) {
  ushort4 q; q.x = f2b(a); q.y = f2b(b); q.z = f2b(c); q.w = f2b(d);
  *(ushort4*)p = q;
}

__device__ __forceinline__ float waveSum(float v) {
  #pragma unroll
  for (int o = 32; o > 0; o >>= 1) v += __shfl_xor(v, o);
  return v;
}
__device__ __forceinline__ float waveMax(float v) {
  #pragma unroll
  for (int o = 32; o > 0; o >>= 1) v = fmaxf(v, __shfl_xor(v, o));
  return v;
}
__device__ __forceinline__ float blockSum256(float v) {
  __shared__ float sm[4];
  v = waveSum(v);
  if ((threadIdx.x & 63) == 0) sm[threadIdx.x >> 6] = v;
  __syncthreads();
  float r = sm[0] + sm[1] + sm[2] + sm[3];
  __syncthreads();
  return r;
}
__device__ __forceinline__ float blockMax256(float v) {
  __shared__ float sm[4];
  v = waveMax(v);
  if ((threadIdx.x & 63) == 0) sm[threadIdx.x >> 6] = v;
  __syncthreads();
  float r = fmaxf(fmaxf(sm[0], sm[1]), fmaxf(sm[2], sm[3]));
  __syncthreads();
  return r;
}

// ---------------- MFMA split-bf16 GEMM ----------------
// C[b] = A[b] @ B[b] (+ biasRow per-M) (+ addMat) ; fp32 in/out, bf16-limb MFMA inside.
// BM = 128, BN = 32*NF, BK = 32. 256 threads = 4 waves (2x2), wave tile 64 x (16*NF).
// LIMBS=2: products hi*hi, hi*lo, lo*hi (~16-bit mantissa). LIMBS=3: 6 products (~fp32).

__device__ __forceinline__ f32x4 mfma_bf16_16x16x32(short8v a, short8v b, f32x4 c) {
  asm("v_mfma_f32_16x16x32_bf16 %0, %1, %2, %0" : "+v"(c) : "v"(a), "v"(b));
  return c;
}

__device__ __forceinline__ int fsw(int r) { return (r ^ (r >> 2) ^ (r >> 4)) & 3; }

template<int LIMBS>
__device__ __forceinline__ void splitbf(float x, u16* out) {
  float r = x;
  #pragma unroll
  for (int li = 0; li < LIMBS; ++li) {
    u16 hb = f2b(r);
    out[li] = hb;
    if (li + 1 < LIMBS) r -= b2f(hb);
  }
}

template<int NF, int LIMBS, bool TRANSB, bool ATOMIC>
__global__ __launch_bounds__(256, 2) void gemm_mfma(
    const float* __restrict__ A, const float* __restrict__ B, float* __restrict__ C,
    int N, int K,
    long long sA, long long sB, long long sC,
    const float* __restrict__ addMat, long long sAdd,
    const float* __restrict__ biasRow, long long sBias,
    int kChunk, int numKS)
{
  static_assert(NF == 4 || NF == 8, "NF");
  static_assert(!TRANSB || NF == 4, "TRANSB tile assumes BN==128");
  constexpr int BN = 32 * NF;
  // element (row,k) stored at column ((k>>3) ^ fsw(row))*8 + (k&7); stride 40 ushorts
  // (80 B) makes b128 frag reads/writes bank-uniform.
  __shared__ __align__(16) u16 Asm_[LIMBS][128][40];
  __shared__ __align__(16) u16 Bsm_[LIMBS][BN][40];

  const int t = threadIdx.x;
  const int bz = blockIdx.z;
  const int b = bz / numKS, ks = bz - b * numKS;
  A += b * sA; B += b * sB; C += b * sC;
  const int m0 = blockIdx.y * 128, n0 = blockIdx.x * BN;
  const int kBeg = ks * kChunk;
  const int kEnd = (kBeg + kChunk < K) ? (kBeg + kChunk) : K;

  const int w = t >> 6, lane = t & 63;
  const int wr = w >> 1, wc = w & 1;
  const int lr = lane & 15, lq = lane >> 4;

  const int sar = t >> 1, sak = (t & 1) * 16;   // A (and TRANSB-B) staging map
  const int kg = t >> 5, ng = t & 31;           // non-trans B staging map

  float ra[16];
  float rb[32];

  auto loadA = [&](int k0) {
    const float* p = A + (long long)(m0 + sar) * K + (k0 + sak);
    #pragma unroll
    for (int i = 0; i < 4; ++i) {
      float4 v = *(const float4*)(p + i * 4);
      ra[i*4+0] = v.x; ra[i*4+1] = v.y; ra[i*4+2] = v.z; ra[i*4+3] = v.w;
    }
  };
  auto loadB = [&](int k0) {
    if constexpr (TRANSB) {
      const float* p = B + (long long)(n0 + sar) * K + (k0 + sak);
      #pragma unroll
      for (int i = 0; i < 4; ++i) {
        float4 v = *(const float4*)(p + i * 4);
        rb[i*4+0] = v.x; rb[i*4+1] = v.y; rb[i*4+2] = v.z; rb[i*4+3] = v.w;
      }
    } else {
      const float* p = B + (long long)(k0 + kg * 4) * N + (n0 + ng * 8);
      #pragma unroll
      for (int i = 0; i < 4; ++i) {
        float4 v0 = *(const float4*)(p + (long long)i * N);
        float4 v1 = *(const float4*)(p + (long long)i * N + 4);
        rb[i*8+0]=v0.x; rb[i*8+1]=v0.y; rb[i*8+2]=v0.z; rb[i*8+3]=v0.w;
        rb[i*8+4]=v1.x; rb[i*8+5]=v1.y; rb[i*8+6]=v1.z; rb[i*8+7]=v1.w;
      }
    }
  };

  auto stage = [&]() {
    {   // A: rows sar, k-local sak..sak+15 -> two swizzled 8-blocks
      const int f = fsw(sar);
      #pragma unroll
      for (int h = 0; h < 2; ++h) {
        const int blk = (sak >> 3) + h;
        const int col = ((blk ^ f) << 3);
        short8v v[LIMBS];
        #pragma unroll
        for (int j = 0; j < 8; ++j) {
          u16 lim[3];
          splitbf<LIMBS>(ra[h*8+j], lim);
          #pragma unroll
          for (int li = 0; li < LIMBS; ++li) v[li][j] = (short)lim[li];
        }
        #pragma unroll
        for (int li = 0; li < LIMBS; ++li)
          *(short8v*)&Asm_[li][sar][col] = v[li];
      }
    }
    if constexpr (TRANSB) {
      const int f = fsw(sar);
      #pragma unroll
      for (int h = 0; h < 2; ++h) {
        const int blk = (sak >> 3) + h;
        const int col = ((blk ^ f) << 3);
        short8v v[LIMBS];
        #pragma unroll
        for (int j = 0; j < 8; ++j) {
          u16 lim[3];
          splitbf<LIMBS>(rb[h*8+j], lim);
          #pragma unroll
          for (int li = 0; li < LIMBS; ++li) v[li][j] = (short)lim[li];
        }
        #pragma unroll
        for (int li = 0; li < LIMBS; ++li)
          *(short8v*)&Bsm_[li][sar][col] = v[li];
      }
    } else {
      // transpose 4k x 8n block into n-major LDS, 4 consecutive k per b64 write
      #pragma unroll
      for (int j = 0; j < 8; ++j) {
        const int n = ng * 8 + j;
        const int col = (((kg >> 1) ^ fsw(n)) << 3) + (kg & 1) * 4;
        short4v v[LIMBS];
        #pragma unroll
        for (int i = 0; i < 4; ++i) {
          u16 lim[3];
          splitbf<LIMBS>(rb[i*8+j], lim);
          #pragma unroll
          for (int li = 0; li < LIMBS; ++li) v[li][i] = (short)lim[li];
        }
        #pragma unroll
        for (int li = 0; li < LIMBS; ++li)
          *(short4v*)&Bsm_[li][n][col] = v[li];
      }
    }
  };

  f32x4 acc[4][NF];
  #pragma unroll
  for (int im = 0; im < 4; ++im)
    #pragma unroll
    for (int in = 0; in < NF; ++in)
      acc[im][in] = f32x4{0.f, 0.f, 0.f, 0.f};

  loadA(kBeg); loadB(kBeg);
  for (int k0 = kBeg; k0 < kEnd; k0 += 32) {
    stage();
    if (k0 + 32 < kEnd) { loadA(k0 + 32); loadB(k0 + 32); }
    __syncthreads();
    short8v af[LIMBS][4];
    #pragma unroll
    for (int im = 0; im < 4; ++im) {
      const int r = wr * 64 + im * 16 + lr;
      const int col = ((lq ^ fsw(r)) << 3);
      #pragma unroll
      for (int li = 0; li < LIMBS; ++li)
        af[li][im] = *(const short8v*)&Asm_[li][r][col];
    }
    #pragma unroll
    for (int in = 0; in < NF; ++in) {
      const int rB = wc * NF * 16 + in * 16 + lr;
      const int colB = ((lq ^ fsw(rB)) << 3);
      short8v bf[LIMBS];
      #pragma unroll
      for (int li = 0; li < LIMBS; ++li)
        bf[li] = *(const short8v*)&Bsm_[li][rB][colB];
      #pragma unroll
      for (int im = 0; im < 4; ++im) {
        #pragma unroll
        for (int i = 0; i < LIMBS; ++i)
          #pragma unroll
          for (int j = 0; j < LIMBS; ++j)
            if (i + j < LIMBS)   // keep limb products down to ~2^-17 (L=2) / 2^-26 (L=3)
              acc[im][in] = mfma_bf16_16x16x32(af[i][im], bf[j], acc[im][in]);
      }
    }
    __syncthreads();
  }
  asm volatile("s_nop 7\n\ts_nop 7\n\ts_nop 7");  // MFMA->VALU/VMEM read hazard guard

  #pragma unroll
  for (int im = 0; im < 4; ++im) {
    #pragma unroll
    for (int in = 0; in < NF; ++in) {
      const f32x4 a = acc[im][in];
      const int gc = n0 + wc * NF * 16 + in * 16 + lr;   // C/D: col = lane&15
      #pragma unroll
      for (int p = 0; p < 4; ++p) {
        const int gr = m0 + wr * 64 + im * 16 + lq * 4 + p;  // row = (lane>>4)*4+reg
        const long long idx = (long long)gr * N + gc;
        if constexpr (ATOMIC) {
          atomicAdd(&C[idx], a[p]);
        } else {
          float v = a[p];
          if (biasRow) v += biasRow[b * sBias + gr];
          if (addMat)  v += addMat[b * sAdd + idx];
          C[idx] = v;
        }
      }
    }
  }
}

// ---------------- generic 64x64 tiled GEMM, fp32 (kept for small GEMMs + fallback) ----
template<typename TA, typename TB, typename TO, bool TRANSB>
__global__ __launch_bounds__(256) void gemm64(
    const TA* __restrict__ A, const TB* __restrict__ B, TO* __restrict__ C,
    int M, int N, int K,
    long long sA, long long sB, long long sC,
    const float* __restrict__ addMat, long long sAdd,
    const float* __restrict__ biasRow, long long sBias)
{
  const int bz = blockIdx.z;
  A += (long long)bz * sA;
  B += (long long)bz * sB;
  C += (long long)bz * sC;
  const int m0 = blockIdx.y * 64, n0 = blockIdx.x * 64;
  __shared__ __align__(16) float As[16][64];
  __shared__ __align__(16) float Bs[16][64];
  const int t = threadIdx.x;
  const int lr = t >> 2, lk = (t & 3) << 2;
  const int tm = (t >> 4) << 2, tn = (t & 15) << 2;
  float acc[4][4] = {};
  for (int k0 = 0; k0 < K; k0 += 16) {
    {
      float4 a = load4(A + (long long)(m0 + lr) * K + (k0 + lk));
      As[lk + 0][lr] = a.x; As[lk + 1][lr] = a.y; As[lk + 2][lr] = a.z; As[lk + 3][lr] = a.w;
    }
    if (TRANSB) {
      float4 b = load4(B + (long long)(n0 + lr) * K + (k0 + lk));
      Bs[lk + 0][lr] = b.x; Bs[lk + 1][lr] = b.y; Bs[lk + 2][lr] = b.z; Bs[lk + 3][lr] = b.w;
    } else {
      const int kr = t >> 4, nc = (t & 15) << 2;
      float4 b = load4(B + (long long)(k0 + kr) * N + (n0 + nc));
      *(float4*)&Bs[kr][nc] = b;
    }
    __syncthreads();
    #pragma unroll
    for (int kk = 0; kk < 16; ++kk) {
      const float4 av = *(const float4*)&As[kk][tm];
      const float4 bv = *(const float4*)&Bs[kk][tn];
      acc[0][0] = fmaf(av.x, bv.x, acc[0][0]);
      acc[0][1] = fmaf(av.x, bv.y, acc[0][1]);
      acc[0][2] = fmaf(av.x, bv.z, acc[0][2]);
      acc[0][3] = fmaf(av.x, bv.w, acc[0][3]);
      acc[1][0] = fmaf(av.y, bv.x, acc[1][0]);
      acc[1][1] = fmaf(av.y, bv.y, acc[1][1]);
      acc[1][2] = fmaf(av.y, bv.z, acc[1][2]);
      acc[1][3] = fmaf(av.y, bv.w, acc[1][3]);
      acc[2][0] = fmaf(av.z, bv.x, acc[2][0]);
      acc[2][1] = fmaf(av.z, bv.y, acc[2][1]);
      acc[2][2] = fmaf(av.z, bv.z, acc[2][2]);
      acc[2][3] = fmaf(av.z, bv.w, acc[2][3]);
      acc[3][0] = fmaf(av.w, bv.x, acc[3][0]);
      acc[3][1] = fmaf(av.w, bv.y, acc[3][1]);
      acc[3][2] = fmaf(av.w, bv.z, acc[3][2]);
      acc[3][3] = fmaf(av.w, bv.w, acc[3][3]);
    }
    __syncthreads();
  }
  #pragma unroll
  for (int i = 0; i < 4; ++i) {
    const int m = m0 + tm + i;
    float bias = biasRow ? biasRow[bz * sBias + m] : 0.f;
    float v0 = acc[i][0] + bias, v1 = acc[i][1] + bias;
    float v2 = acc[i][2] + bias, v3 = acc[i][3] + bias;
    if (addMat) {
      const float* ap = addMat + bz * sAdd + (long long)m * N + (n0 + tn);
      float4 a4 = load4(ap);
      v0 += a4.x; v1 += a4.y; v2 += a4.z; v3 += a4.w;
    }
    store4(C + (long long)m * N + (n0 + tn), v0, v1, v2, v3);
  }
}

// ---------------- small kernels ----------------
__global__ __launch_bounds__(256) void rowsum_kernel(const float* __restrict__ X,
                                                     float* __restrict__ s, int N) {
  long long row = blockIdx.x;
  const float* p = X + row * N;
  float acc = 0.f;
  for (int i = threadIdx.x; i < N; i += 256) acc += p[i];
  acc = blockSum256(acc);
  if (threadIdx.x == 0) s[row] = acc;
}

__global__ __launch_bounds__(256) void gemv512_kernel(const float* __restrict__ W,
                                                      const float* __restrict__ s,
                                                      float* __restrict__ out) {
  int b = blockIdx.x;
  __shared__ float ssm[Cc];
  for (int i = threadIdx.x; i < Cc; i += 256) ssm[i] = s[b * Cc + i];
  __syncthreads();
  int i = threadIdx.x;
  const float* wr = W + i * Cc;
  float acc = 0.f;
  for (int k = 0; k < Cc; ++k) acc = fmaf(wr[k], ssm[k], acc);
  out[b * C1 + i] = acc;
}

__global__ __launch_bounds__(256) void softmax_kernel(float* __restrict__ L,
    const float* __restrict__ bth, const float* __restrict__ bph,
    const float* __restrict__ u, const float* __restrict__ v) {
  int row = blockIdx.x;                 // b*256 + i
  int b = row >> 8, i = row & 255;
  int j = threadIdx.x;
  float bt = bth[i], bp = bph[j];
  long long idx = (long long)row * C1 + j;
  float val = L[idx] + bt * v[b * C1 + j] + u[b * C1 + i] * bp + (float)Nn * bt * bp;
  float mx = blockMax256(val);
  float p = expf(val - mx);
  float sm = blockSum256(p);
  L[idx] = p / sm;
}

__global__ __launch_bounds__(256) void w_kernel(const float* __restrict__ f,
                                                const float* __restrict__ bg,
                                                float* __restrict__ w) {
  int b = blockIdx.x;
  __shared__ float bgs[C1];
  bgs[threadIdx.x] = bg[threadIdx.x];
  __syncthreads();
  int i = threadIdx.x;
  const float* fr = f + ((long long)b * C1 + i) * C1;
  float acc = 0.f;
  for (int j = 0; j < C1; ++j) acc = fmaf(fr[j], bgs[j], acc);
  w[b * C1 + i] = acc;
}

__global__ __launch_bounds__(256) void q_kernel(const float* __restrict__ W2,
                                                const float* __restrict__ b2v,
                                                const float* __restrict__ w,
                                                float* __restrict__ q) {
  int gi = blockIdx.x * 256 + threadIdx.x;
  int b = gi >> 9, c = gi & 511;
  __shared__ float wsm[C1];
  wsm[threadIdx.x] = w[b * C1 + threadIdx.x];
  __syncthreads();
  const float* wr = W2 + c * C1;
  float acc = b2v[c];
  for (int i = 0; i < C1; ++i) acc = fmaf(wr[i], wsm[i], acc);
  q[gi] = acc;
}

template<typename ZT>
__global__ __launch_bounds__(256) void enc_kernel(
    const ZT* __restrict__ zq,      // [B][D][N]
    const float* __restrict__ cw,   // [K][D]
    const float* __restrict__ sc,   // [K]
    float* __restrict__ Eraw,       // [B][K][D] pre-zeroed
    float* __restrict__ Asum)       // [B][K]    pre-zeroed
{
  __shared__ float csm[Kk][Dd + 1];
  __shared__ float cc[Kk], ssm[Kk];
  __shared__ float sA[Kk][256 + 1];
  __shared__ float zs[Dd][17];
  const int tid = threadIdx.x;
  const int b = blockIdx.y;
  const int n0 = blockIdx.x * 256;

  #pragma unroll
  for (int r = 0; r < 16; ++r) {
    int idx = r * 256 + tid;
    csm[idx >> 7][idx & 127] = cw[idx];
  }
  if (tid < Kk) ssm[tid] = sc[tid];
  __syncthreads();
  if (tid < Kk) {
    float a = 0.f;
    for (int d = 0; d < Dd; ++d) { float cv = csm[tid][d]; a = fmaf(cv, cv, a); }
    cc[tid] = a;
  }
  __syncthreads();

  const int n = n0 + tid;
  const ZT* zp = zq + (long long)b * Dd * Nn + n;
  float dots[Kk];
  #pragma unroll
  for (int k = 0; k < Kk; ++k) dots[k] = 0.f;
  float xx = 0.f;
  for (int d = 0; d < Dd; ++d) {
    float xv = b2fOrF(zp[(long long)d * Nn]);
    xx = fmaf(xv, xv, xx);
    #pragma unroll
    for (int k = 0; k < Kk; ++k) dots[k] = fmaf(csm[k][d], xv, dots[k]);
  }
  float mx = -1e30f;
  #pragma unroll
  for (int k = 0; k < Kk; ++k) {
    float l = ssm[k] * (xx - 2.f * dots[k] + cc[k]);
    dots[k] = l;
    mx = fmaxf(mx, l);
  }
  float sum = 0.f;
  #pragma unroll
  for (int k = 0; k < Kk; ++k) { float p = expf(dots[k] - mx); dots[k] = p; sum += p; }
  float inv = 1.f / sum;
  #pragma unroll
  for (int k = 0; k < Kk; ++k) sA[k][tid] = dots[k] * inv;
  __syncthreads();
  if (tid < Kk) {
    float s = 0.f;
    for (int p = 0; p < 256; ++p) s += sA[tid][p];
    atomicAdd(&Asum[b * Kk + tid], s);
  }

  float acc[16];
  #pragma unroll
  for (int j = 0; j < 16; ++j) acc[j] = 0.f;
  const int k = tid & 31, d0 = (tid >> 5) * 16;
  const int ldd = tid >> 1, lpx = (tid & 1) * 8;
  for (int it = 0; it < 16; ++it) {
    __syncthreads();
    {
      const ZT* src = zq + ((long long)b * Dd + ldd) * Nn + n0 + it * 16 + lpx;
      float4 a4 = load4(src);
      float4 b4 = load4(src + 4);
      zs[ldd][lpx + 0] = a4.x; zs[ldd][lpx + 1] = a4.y;
      zs[ldd][lpx + 2] = a4.z; zs[ldd][lpx + 3] = a4.w;
      zs[ldd][lpx + 4] = b4.x; zs[ldd][lpx + 5] = b4.y;
      zs[ldd][lpx + 6] = b4.z; zs[ldd][lpx + 7] = b4.w;
    }
    __syncthreads();
    #pragma unroll
    for (int p = 0; p < 16; ++p) {
      float a = sA[k][it * 16 + p];
      #pragma unroll
      for (int j = 0; j < 16; ++j) acc[j] = fmaf(a, zs[d0 + j][p], acc[j]);
    }
  }
  float* Ep = Eraw + ((long long)b * Kk + k) * Dd + d0;
  #pragma unroll
  for (int j = 0; j < 16; ++j) atomicAdd(Ep + j, acc[j]);
}

__global__ __launch_bounds__(256) void bn_kernel(const float* __restrict__ Eraw,
    const float* __restrict__ Asum, const float* __restrict__ cw, float* __restrict__ Es) {
  int k = blockIdx.x, tid = threadIdx.x;
  float vals[4], s = 0.f, s2 = 0.f;
  #pragma unroll
  for (int r = 0; r < 4; ++r) {
    int i = r * 256 + tid;
    int b = i >> 7, d = i & 127;
    float e = Eraw[((long long)b * Kk + k) * Dd + d] - Asum[b * Kk + k] * cw[k * Dd + d];
    vals[r] = e; s += e; s2 = fmaf(e, e, s2);
  }
  s = blockSum256(s);
  s2 = blockSum256(s2);
  float mean = s * (1.f / 1024.f);
  float var = fmaxf(s2 * (1.f / 1024.f) - mean * mean, 0.f);
  float rs = rsqrtf(var + 1e-5f);
  #pragma unroll
  for (int r = 0; r < 4; ++r) {
    int i = r * 256 + tid;
    int b = i >> 7, d = i & 127;
    float e = (vals[r] - mean) * rs;
    if (e > 0.f) atomicAdd(&Es[b * Dd + d], e);
  }
}

__global__ __launch_bounds__(256) void gamma_kernel(const float* __restrict__ Es,
    const float* __restrict__ Wfc, const float* __restrict__ bfc, float* __restrict__ gam) {
  int gi = blockIdx.x * 256 + threadIdx.x;
  int b = gi >> 9, c = gi & 511;
  __shared__ float esm[Dd];
  if (threadIdx.x < Dd) esm[threadIdx.x] = Es[b * Dd + threadIdx.x];
  __syncthreads();
  const float* wr = Wfc + c * Dd;
  float acc = bfc[c];
  for (int d = 0; d < Dd; ++d) acc = fmaf(wr[d], esm[d], acc);
  gam[gi] = 1.f / (1.f + expf(-acc));
}

__global__ __launch_bounds__(256) void scaleout_f32(float* __restrict__ out,
    const float* __restrict__ gam) {
  unsigned int idx = blockIdx.x * 256u + threadIdx.x;
  unsigned int f = idx * 4u;
  unsigned int bc = f / (unsigned)Nn;
  float g = gam[bc];
  float4 zv = *(const float4*)(out + f);
  store4(out + f, zv.x * g, zv.y * g, zv.z * g, zv.w * g);
}

// ---------------- host launcher ----------------
extern "C" void kernel_launch(void* const* d_in, const int* in_sizes, int n_in,
                              void* d_out, int out_size, void* d_ws, size_t ws_size,
                              hipStream_t stream) {
  const float* X   = (const float*)d_in[0];
  const float* Wth = (const float*)d_in[1];
  const float* bth = (const float*)d_in[2];
  const float* Wph = (const float*)d_in[3];
  const float* bph = (const float*)d_in[4];
  const float* Wg  = (const float*)d_in[5];
  const float* bg  = (const float*)d_in[6];
  const float* W2  = (const float*)d_in[7];
  const float* b2v = (const float*)d_in[8];
  const float* W3  = (const float*)d_in[9];
  const float* b3v = (const float*)d_in[10];
  const float* CW  = (const float*)d_in[11];
  const float* SC  = (const float*)d_in[12];
  const float* Wfc = (const float*)d_in[13];
  const float* bfc = (const float*)d_in[14];
  float* out = (float*)d_out;
  float* wsf = (float*)d_ws;

  const long long szL   = (long long)Bb * C1 * C1;
  const long long szRA  = (long long)Bb * Cc * Cc;
  const long long szRB  = (long long)Bb * C1 * Cc;
  long long off = 0;
  float* s_   = wsf + off; off += Bb * Cc;
  float* u_   = wsf + off; off += Bb * C1;
  float* v_   = wsf + off; off += Bb * C1;
  float* w_   = wsf + off; off += Bb * C1;
  float* q_   = wsf + off; off += Bb * Cc;
  float* Eraw_= wsf + off; off += (long long)Bb * Kk * Dd;
  float* Es_  = wsf + off; off += Bb * Dd;
  float* Asum_= wsf + off; off += Bb * Kk;
  float* gam_ = wsf + off; off += Bb * Cc;
  float* L_   = wsf + off; off += szL;
  float* regA = wsf + off; off += szRA;
  float* regB = wsf + off; off += szRB;
  const long long baseFloats = off;
  float* zqf  = wsf + off;
  u16*   zqh  = (u16*)(wsf + off);
  const size_t needF32 = (size_t)(baseFloats + (long long)Bb * Dd * Nn) * 4;
  const bool zqIsF32 = ws_size >= needF32;

  const long long strX = (long long)Cc * Nn;
  const long long sG = (long long)Cc * Cc;
  const long long sU = (long long)C1 * Cc;
  const long long sL = (long long)C1 * C1;

  rowsum_kernel<<<Bb * Cc, 256, 0, stream>>>(X, s_, Nn);
  // G = X X^T  -> regA : MFMA 3-limb split (~fp32-exact), split-K=4, atomic accumulate
  hipMemsetAsync(regA, 0, (size_t)szRA * 4, stream);
  gemm_mfma<4, 3, true, true><<<dim3(4, 4, Bb * 4), 256, 0, stream>>>(
      X, X, regA, Cc, Nn, strX, strX, sG, nullptr, 0, nullptr, 0, Nn / 4, 4);
  // U = Wth @ G -> regB
  gemm64<float, float, float, false><<<dim3(8, 4, Bb), 256, 0, stream>>>(
      Wth, regA, regB, C1, Cc, Cc, 0, sG, sU, nullptr, 0, nullptr, 0);
  gemv512_kernel<<<Bb, 256, 0, stream>>>(Wth, s_, u_);
  gemv512_kernel<<<Bb, 256, 0, stream>>>(Wph, s_, v_);
  // L = U @ Wph^T
  gemm64<float, float, float, true><<<dim3(4, 4, Bb), 256, 0, stream>>>(
      regB, Wph, L_, C1, C1, Cc, sU, 0, sL, nullptr, 0, nullptr, 0);
  softmax_kernel<<<Bb * C1, 256, 0, stream>>>(L_, bth, bph, u_, v_);
  w_kernel<<<Bb, 256, 0, stream>>>(L_, bg, w_);
  // Mm = f @ Wg -> regB (U dead)
  gemm64<float, float, float, false><<<dim3(8, 4, Bb), 256, 0, stream>>>(
      L_, Wg, regB, C1, Cc, C1, sL, 0, sU, nullptr, 0, nullptr, 0);
  q_kernel<<<16, 256, 0, stream>>>(W2, b2v, w_, q_);
  // P = W2 @ Mm -> regA (G dead)
  gemm64<float, float, float, false><<<dim3(8, 8, Bb), 256, 0, stream>>>(
      W2, regB, regA, Cc, Cc, C1, 0, sU, sG, nullptr, 0, nullptr, 0);
  // z = P @ X + X + q  -> out : MFMA 2-limb split
  gemm_mfma<8, 2, false, false><<<dim3(36, 4, Bb), 256, 0, stream>>>(
      regA, X, out, Nn, Cc, sG, strX, strX, X, strX, q_, Cc, Cc, 1);
  // zq = W3 @ z + b3
  hipMemsetAsync(Eraw_, 0, (size_t)(Bb * Kk * Dd + Bb * Dd + Bb * Kk) * 4, stream);
  if (zqIsF32) {
    gemm_mfma<8, 2, false, false><<<dim3(36, 1, Bb), 256, 0, stream>>>(
        W3, out, zqf, Nn, Cc, 0, strX, (long long)Dd * Nn, nullptr, 0, b3v, 0, Cc, 1);
    enc_kernel<float><<<dim3(36, Bb), 256, 0, stream>>>(zqf, CW, SC, Eraw_, Asum_);
  } else {
    gemm64<float, float, u16, false><<<dim3(144, 2, Bb), 256, 0, stream>>>(
        W3, out, zqh, Dd, Nn, Cc, 0, strX, (long long)Dd * Nn, nullptr, 0, b3v, 0);
    enc_kernel<u16><<<dim3(36, Bb), 256, 0, stream>>>(zqh, CW, SC, Eraw_, Asum_);
  }
  bn_kernel<<<Kk, 256, 0, stream>>>(Eraw_, Asum_, CW, Es_);
  gamma_kernel<<<16, 256, 0, stream>>>(Es_, Wfc, bfc, gam_);
  const unsigned int n4 = (unsigned)(Bb * Cc * Nn / 4);
  scaleout_f32<<<n4 / 256, 256, 0, stream>>>(out, gam_);
  (void)in_sizes; (void)n_in; (void)out_size;
}

// Round 2
// 1119.871 us; speedup vs baseline: 1.7328x; 1.0885x over previous
//
#include <hip/hip_runtime.h>

// NLCE: non-local (channel attention) + Deep-TEN encoding, B=8 C=512 C1=256 D=128 K=32 N=9216.
// All inputs/outputs fp32. Big GEMMs on matrix cores via 2-limb bf16 split
// (hi/lo via v_cvt_pk_bf16_f32; products hi*hi+hi*lo+lo*hi, ~1e-5 rel).
// Algebra: U = (Wth X) X^T  (G = X X^T never materialized);
//          z = (W2 f Wg + I) X + q 1^T;  zq = (W3 (P+I)) X + (W3 q + b3).

typedef unsigned short u16;

#define Bb 8
#define Cc 512
#define C1 256
#define Dd 128
#define Kk 32
#define Nn 9216

typedef __attribute__((ext_vector_type(8))) short short8v;
typedef __attribute__((ext_vector_type(4))) short short4v;
typedef __attribute__((ext_vector_type(4))) float f32x4;

__device__ __forceinline__ float b2f(u16 u) {
  union { unsigned int i; float f; } v; v.i = ((unsigned int)u) << 16; return v.f;
}
__device__ __forceinline__ u16 f2b(float f) {
  union { float f; unsigned int i; } v; v.f = f;
  unsigned int x = v.i;
  return (u16)((x + 0x7fffu + ((x >> 16) & 1u)) >> 16);  // RNE
}

__device__ __forceinline__ float b2fOrF(float x) { return x; }
__device__ __forceinline__ float b2fOrF(u16 x) { return b2f(x); }

__device__ __forceinline__ float4 load4(const float* p) { return *(const float4*)p; }
__device__ __forceinline__ float4 load4(const u16* p) {
  ushort4 q = *(const ushort4*)p;
  return make_float4(b2f(q.x), b2f(q.y), b2f(q.z), b2f(q.w));
}
__device__ __forceinline__ void store4(float* p, float a, float b, float c, float d) {
  *(float4*)p = make_float4(a, b, c, d);
}

__device__ __forceinline__ float waveSum(float v) {
  #pragma unroll
  for (int o = 32; o > 0; o >>= 1) v += __shfl_xor(v, o);
  return v;
}
__device__ __forceinline__ float waveMax(float v) {
  #pragma unroll
  for (int o = 32; o > 0; o >>= 1) v = fmaxf(v, __shfl_xor(v, o));
  return v;
}
__device__ __forceinline__ float blockSum256(float v) {
  __shared__ float sm[4];
  v = waveSum(v);
  if ((threadIdx.x & 63) == 0) sm[threadIdx.x >> 6] = v;
  __syncthreads();
  float r = sm[0] + sm[1] + sm[2] + sm[3];
  __syncthreads();
  return r;
}
__device__ __forceinline__ float blockMax256(float v) {
  __shared__ float sm[4];
  v = waveMax(v);
  if ((threadIdx.x & 63) == 0) sm[threadIdx.x >> 6] = v;
  __syncthreads();
  float r = fmaxf(fmaxf(sm[0], sm[1]), fmaxf(sm[2], sm[3]));
  __syncthreads();
  return r;
}

// ---------------- MFMA split-bf16 GEMM ----------------
__device__ __forceinline__ f32x4 mfma_bf16_16x16x32(short8v a, short8v b, f32x4 c) {
  asm("v_mfma_f32_16x16x32_bf16 %0, %1, %2, %0" : "+v"(c) : "v"(a), "v"(b));
  return c;
}

__device__ __forceinline__ int fsw(int r) { return (r ^ (r >> 2) ^ (r >> 4)) & 3; }

// 2 floats -> packed bf16 hi limbs (h) and lo limbs (l), 1 cvt_pk each + exact residual
__device__ __forceinline__ void cvt2(float x0, float x1, unsigned int& h, unsigned int& l) {
  asm("v_cvt_pk_bf16_f32 %0, %1, %2" : "=v"(h) : "v"(x0), "v"(x1));
  union { unsigned int u; float f; } fa, fb;
  fa.u = h << 16; fb.u = h & 0xffff0000u;
  float r0 = x0 - fa.f, r1 = x1 - fb.f;
  asm("v_cvt_pk_bf16_f32 %0, %1, %2" : "=v"(l) : "v"(r0), "v"(r1));
}

__device__ __forceinline__ void storeC(float* p, float v) { *p = v; }
__device__ __forceinline__ void storeC(u16* p, float v) { *p = f2b(v); }

// C[b] = A[b] @ B[b] (+ biasRow per-M) ; fp32 in, TO out, 2-limb bf16 MFMA inside.
// BM = 128, BN = 32*NF, BK = 32. 256 threads = 4 waves (2x2), wave tile 64 x (16*NF).
// Flat 1-D grid with XCD-chunk swizzle; decomposition: m-index fastest, batch slowest.
template<typename TO, int NF, bool TRANSB, bool ATOMIC>
__global__ __launch_bounds__(256, 2) void gemm_mfma(
    const float* __restrict__ A, const float* __restrict__ B, TO* __restrict__ C,
    int N, int K,
    long long sA, long long sB, long long sC,
    const float* __restrict__ biasRow, long long sBias,
    int kChunk, int numKS, int gnx, int gny)
{
  static_assert(NF == 4 || NF == 8, "NF");
  static_assert(!TRANSB || NF == 4, "TRANSB tile assumes BN==128");
  static_assert(!ATOMIC || __is_same(TO, float), "atomic path is fp32");
  constexpr int BN = 32 * NF;
  // element (row,k) stored at column ((k>>3) ^ fsw(row))*8 + (k&7); stride 40 ushorts.
  __shared__ __align__(16) u16 Asm_[2][128][40];
  __shared__ __align__(16) u16 Bsm_[2][BN][40];

  int id = blockIdx.x;
  {
    const int nwg = gridDim.x;
    if ((nwg & 7) == 0) id = (id & 7) * (nwg >> 3) + (id >> 3);  // XCD chunk swizzle
  }
  const int per = gnx * gny;
  const int bz = id / per;
  const int rem = id - bz * per;
  const int by = rem % gny;        // m-block (fastest: B-slab reuse on one XCD)
  const int bx = rem / gny;        // n-block
  const int b = bz / numKS, ks = bz - b * numKS;
  A += b * sA; B += b * sB; C += b * sC;
  const int m0 = by * 128, n0 = bx * BN;
  const int kBeg = ks * kChunk;
  const int kEnd = (kBeg + kChunk < K) ? (kBeg + kChunk) : K;

  const int t = threadIdx.x;
  const int w = t >> 6, lane = t & 63;
  const int wr = w >> 1, wc = w & 1;
  const int lr = lane & 15, lq = lane >> 4;

  const int sar = t >> 1, sak = (t & 1) * 16;   // A (and TRANSB-B) staging map
  const int kg = t >> 5, ng = t & 31;           // non-trans B staging map

  float ra[16];
  float rb[32];

  auto loadA = [&](int k0) {
    const float* p = A + (long long)(m0 + sar) * K + (k0 + sak);
    #pragma unroll
    for (int i = 0; i < 4; ++i) {
      float4 v = *(const float4*)(p + i * 4);
      ra[i*4+0] = v.x; ra[i*4+1] = v.y; ra[i*4+2] = v.z; ra[i*4+3] = v.w;
    }
  };
  auto loadB = [&](int k0) {
    if constexpr (TRANSB) {
      const float* p = B + (long long)(n0 + sar) * K + (k0 + sak);
      #pragma unroll
      for (int i = 0; i < 4; ++i) {
        float4 v = *(const float4*)(p + i * 4);
        rb[i*4+0] = v.x; rb[i*4+1] = v.y; rb[i*4+2] = v.z; rb[i*4+3] = v.w;
      }
    } else {
      const float* p = B + (long long)(k0 + kg * 4) * N + (n0 + ng * 8);
      #pragma unroll
      for (int i = 0; i < 4; ++i) {
        float4 v0 = *(const float4*)(p + (long long)i * N);
        float4 v1 = *(const float4*)(p + (long long)i * N + 4);
        rb[i*8+0]=v0.x; rb[i*8+1]=v0.y; rb[i*8+2]=v0.z; rb[i*8+3]=v0.w;
        rb[i*8+4]=v1.x; rb[i*8+5]=v1.y; rb[i*8+6]=v1.z; rb[i*8+7]=v1.w;
      }
    }
  };

  auto pack8row = [&](const float* s8, u16 (&dstH)[40], u16 (&dstL)[40], int col) {
    union { unsigned int u[4]; short8v v; } H, L;
    #pragma unroll
    for (int p = 0; p < 4; ++p) cvt2(s8[2*p], s8[2*p+1], H.u[p], L.u[p]);
    *(short8v*)&dstH[col] = H.v;
    *(short8v*)&dstL[col] = L.v;
  };

  auto stage = [&]() {
    {   // A rows sar, k-local sak..sak+15 -> two swizzled 8-blocks
      const int f = fsw(sar);
      #pragma unroll
      for (int h = 0; h < 2; ++h) {
        const int col = ((((sak >> 3) + h) ^ f) << 3);
        pack8row(&ra[h*8], Asm_[0][sar], Asm_[1][sar], col);
      }
    }
    if constexpr (TRANSB) {
      const int f = fsw(sar);
      #pragma unroll
      for (int h = 0; h < 2; ++h) {
        const int col = ((((sak >> 3) + h) ^ f) << 3);
        pack8row(&rb[h*8], Bsm_[0][sar], Bsm_[1][sar], col);
      }
    } else {
      // transpose 4k x 8n block into n-major LDS, 4 consecutive k per b64 write
      #pragma unroll
      for (int j = 0; j < 8; ++j) {
        const int n = ng * 8 + j;
        const int col = (((kg >> 1) ^ fsw(n)) << 3) + (kg & 1) * 4;
        union { unsigned int u[2]; short4v v; } H, L;
        #pragma unroll
        for (int p = 0; p < 2; ++p)
          cvt2(rb[(2*p)*8 + j], rb[(2*p+1)*8 + j], H.u[p], L.u[p]);
        *(short4v*)&Bsm_[0][n][col] = H.v;
        *(short4v*)&Bsm_[1][n][col] = L.v;
      }
    }
  };

  f32x4 acc[4][NF];
  #pragma unroll
  for (int im = 0; im < 4; ++im)
    #pragma unroll
    for (int in = 0; in < NF; ++in)
      acc[im][in] = f32x4{0.f, 0.f, 0.f, 0.f};

  loadA(kBeg); loadB(kBeg);
  for (int k0 = kBeg; k0 < kEnd; k0 += 32) {
    stage();
    if (k0 + 32 < kEnd) { loadA(k0 + 32); loadB(k0 + 32); }
    __syncthreads();
    short8v af[2][4];
    #pragma unroll
    for (int im = 0; im < 4; ++im) {
      const int r = wr * 64 + im * 16 + lr;
      const int col = ((lq ^ fsw(r)) << 3);
      af[0][im] = *(const short8v*)&Asm_[0][r][col];
      af[1][im] = *(const short8v*)&Asm_[1][r][col];
    }
    #pragma unroll
    for (int in = 0; in < NF; ++in) {
      const int rB = wc * NF * 16 + in * 16 + lr;
      const int colB = ((lq ^ fsw(rB)) << 3);
      short8v bh = *(const short8v*)&Bsm_[0][rB][colB];
      short8v bl = *(const short8v*)&Bsm_[1][rB][colB];
      #pragma unroll
      for (int im = 0; im < 4; ++im) {
        acc[im][in] = mfma_bf16_16x16x32(af[0][im], bh, acc[im][in]);  // hi*hi
        acc[im][in] = mfma_bf16_16x16x32(af[0][im], bl, acc[im][in]);  // hi*lo
        acc[im][in] = mfma_bf16_16x16x32(af[1][im], bh, acc[im][in]);  // lo*hi
      }
    }
    __syncthreads();
  }
  asm volatile("s_nop 7\n\ts_nop 7\n\ts_nop 7");  // MFMA->VALU/VMEM read hazard guard

  #pragma unroll
  for (int im = 0; im < 4; ++im) {
    #pragma unroll
    for (int in = 0; in < NF; ++in) {
      const f32x4 a = acc[im][in];
      const int gc = n0 + wc * NF * 16 + in * 16 + lr;   // C/D: col = lane&15
      #pragma unroll
      for (int p = 0; p < 4; ++p) {
        const int gr = m0 + wr * 64 + im * 16 + lq * 4 + p;  // row = (lane>>4)*4+reg
        const long long idx = (long long)gr * N + gc;
        if constexpr (ATOMIC) {
          atomicAdd(&C[idx], a[p]);
        } else {
          float v = a[p];
          if (biasRow) v += biasRow[b * sBias + gr];
          storeC(&C[idx], v);
        }
      }
    }
  }
}

// ---------------- generic 64x64 tiled GEMM, fp32 (small GEMMs) ----------------
template<bool TRANSB>
__global__ __launch_bounds__(256) void gemm64(
    const float* __restrict__ A, const float* __restrict__ B, float* __restrict__ C,
    int M, int N, int K,
    long long sA, long long sB, long long sC,
    const float* __restrict__ biasRow, long long sBias)
{
  const int bz = blockIdx.z;
  A += (long long)bz * sA;
  B += (long long)bz * sB;
  C += (long long)bz * sC;
  const int m0 = blockIdx.y * 64, n0 = blockIdx.x * 64;
  __shared__ __align__(16) float As[16][64];
  __shared__ __align__(16) float Bs[16][64];
  const int t = threadIdx.x;
  const int lr = t >> 2, lk = (t & 3) << 2;
  const int tm = (t >> 4) << 2, tn = (t & 15) << 2;
  float acc[4][4] = {};
  for (int k0 = 0; k0 < K; k0 += 16) {
    {
      float4 a = load4(A + (long long)(m0 + lr) * K + (k0 + lk));
      As[lk + 0][lr] = a.x; As[lk + 1][lr] = a.y; As[lk + 2][lr] = a.z; As[lk + 3][lr] = a.w;
    }
    if (TRANSB) {
      float4 b = load4(B + (long long)(n0 + lr) * K + (k0 + lk));
      Bs[lk + 0][lr] = b.x; Bs[lk + 1][lr] = b.y; Bs[lk + 2][lr] = b.z; Bs[lk + 3][lr] = b.w;
    } else {
      const int kr = t >> 4, nc = (t & 15) << 2;
      float4 b = load4(B + (long long)(k0 + kr) * N + (n0 + nc));
      *(float4*)&Bs[kr][nc] = b;
    }
    __syncthreads();
    #pragma unroll
    for (int kk = 0; kk < 16; ++kk) {
      const float4 av = *(const float4*)&As[kk][tm];
      const float4 bv = *(const float4*)&Bs[kk][tn];
      acc[0][0] = fmaf(av.x, bv.x, acc[0][0]);
      acc[0][1] = fmaf(av.x, bv.y, acc[0][1]);
      acc[0][2] = fmaf(av.x, bv.z, acc[0][2]);
      acc[0][3] = fmaf(av.x, bv.w, acc[0][3]);
      acc[1][0] = fmaf(av.y, bv.x, acc[1][0]);
      acc[1][1] = fmaf(av.y, bv.y, acc[1][1]);
      acc[1][2] = fmaf(av.y, bv.z, acc[1][2]);
      acc[1][3] = fmaf(av.y, bv.w, acc[1][3]);
      acc[2][0] = fmaf(av.z, bv.x, acc[2][0]);
      acc[2][1] = fmaf(av.z, bv.y, acc[2][1]);
      acc[2][2] = fmaf(av.z, bv.z, acc[2][2]);
      acc[2][3] = fmaf(av.z, bv.w, acc[2][3]);
      acc[3][0] = fmaf(av.w, bv.x, acc[3][0]);
      acc[3][1] = fmaf(av.w, bv.y, acc[3][1]);
      acc[3][2] = fmaf(av.w, bv.z, acc[3][2]);
      acc[3][3] = fmaf(av.w, bv.w, acc[3][3]);
    }
    __syncthreads();
  }
  #pragma unroll
  for (int i = 0; i < 4; ++i) {
    const int m = m0 + tm + i;
    float bias = biasRow ? biasRow[bz * sBias + m] : 0.f;
    store4(C + (long long)m * N + (n0 + tn),
           acc[i][0] + bias, acc[i][1] + bias, acc[i][2] + bias, acc[i][3] + bias);
  }
}

// ---------------- small kernels ----------------
__global__ __launch_bounds__(256) void rowsum_kernel(const float* __restrict__ X,
                                                     float* __restrict__ s, int N) {
  long long row = blockIdx.x;
  const float* p = X + row * N;
  float acc = 0.f;
  for (int i = threadIdx.x; i < N; i += 256) acc += p[i];
  acc = blockSum256(acc);
  if (threadIdx.x == 0) s[row] = acc;
}

__global__ __launch_bounds__(256) void gemv512_kernel(const float* __restrict__ W,
                                                      const float* __restrict__ s,
                                                      float* __restrict__ out) {
  int b = blockIdx.x;
  __shared__ float ssm[Cc];
  for (int i = threadIdx.x; i < Cc; i += 256) ssm[i] = s[b * Cc + i];
  __syncthreads();
  int i = threadIdx.x;
  const float* wr = W + i * Cc;
  float acc = 0.f;
  for (int k = 0; k < Cc; ++k) acc = fmaf(wr[k], ssm[k], acc);
  out[b * C1 + i] = acc;
}

__global__ __launch_bounds__(256) void softmax_kernel(float* __restrict__ L,
    const float* __restrict__ bth, const float* __restrict__ bph,
    const float* __restrict__ u, const float* __restrict__ v) {
  int row = blockIdx.x;                 // b*256 + i
  int b = row >> 8, i = row & 255;
  int j = threadIdx.x;
  float bt = bth[i], bp = bph[j];
  long long idx = (long long)row * C1 + j;
  float val = L[idx] + bt * v[b * C1 + j] + u[b * C1 + i] * bp + (float)Nn * bt * bp;
  float mx = blockMax256(val);
  float p = expf(val - mx);
  float sm = blockSum256(p);
  L[idx] = p / sm;
}

__global__ __launch_bounds__(256) void w_kernel(const float* __restrict__ f,
                                                const float* __restrict__ bg,
                                                float* __restrict__ w) {
  int b = blockIdx.x;
  __shared__ float bgs[C1];
  bgs[threadIdx.x] = bg[threadIdx.x];
  __syncthreads();
  int i = threadIdx.x;
  const float* fr = f + ((long long)b * C1 + i) * C1;
  float acc = 0.f;
  for (int j = 0; j < C1; ++j) acc = fmaf(fr[j], bgs[j], acc);
  w[b * C1 + i] = acc;
}

__global__ __launch_bounds__(256) void q_kernel(const float* __restrict__ W2,
                                                const float* __restrict__ b2v,
                                                const float* __restrict__ w,
                                                float* __restrict__ q) {
  int gi = blockIdx.x * 256 + threadIdx.x;
  int b = gi >> 9, c = gi & 511;
  __shared__ float wsm[C1];
  wsm[threadIdx.x] = w[b * C1 + threadIdx.x];
  __syncthreads();
  const float* wr = W2 + c * C1;
  float acc = b2v[c];
  for (int i = 0; i < C1; ++i) acc = fmaf(wr[i], wsm[i], acc);
  q[gi] = acc;
}

// P[b] += I  (fold the residual connection into the GEMM operand)
__global__ __launch_bounds__(256) void adddiag_kernel(float* __restrict__ P) {
  int gi = blockIdx.x * 256 + threadIdx.x;   // [0, 8*512)
  int b = gi >> 9, c = gi & 511;
  P[((long long)b * Cc + c) * Cc + c] += 1.f;
}

// zqb[b][d] = b3[d] + sum_c W3[d][c] * q[b][c]
__global__ __launch_bounds__(256) void zqbias_kernel(const float* __restrict__ W3,
    const float* __restrict__ b3, const float* __restrict__ q, float* __restrict__ zqb) {
  int gi = blockIdx.x * 256 + threadIdx.x;   // [0, 1024)
  int b = gi >> 7, d = gi & 127;
  const float* wr = W3 + d * Cc;
  const float* qr = q + b * Cc;
  float acc = b3[d];
  for (int c = 0; c < Cc; ++c) acc = fmaf(wr[c], qr[c], acc);
  zqb[gi] = acc;
}

template<typename ZT>
__global__ __launch_bounds__(256) void enc_kernel(
    const ZT* __restrict__ zq,      // [B][D][N]
    const float* __restrict__ cw,   // [K][D]
    const float* __restrict__ sc,   // [K]
    float* __restrict__ Eraw,       // [B][K][D] pre-zeroed
    float* __restrict__ Asum)       // [B][K]    pre-zeroed
{
  __shared__ float csm[Kk][Dd + 1];
  __shared__ float cc[Kk], ssm[Kk];
  __shared__ float sA[Kk][256 + 1];
  __shared__ float zs[Dd][17];
  const int tid = threadIdx.x;
  const int b = blockIdx.y;
  const int n0 = blockIdx.x * 256;

  #pragma unroll
  for (int r = 0; r < 16; ++r) {
    int idx = r * 256 + tid;
    csm[idx >> 7][idx & 127] = cw[idx];
  }
  if (tid < Kk) ssm[tid] = sc[tid];
  __syncthreads();
  if (tid < Kk) {
    float a = 0.f;
    for (int d = 0; d < Dd; ++d) { float cv = csm[tid][d]; a = fmaf(cv, cv, a); }
    cc[tid] = a;
  }
  __syncthreads();

  const int n = n0 + tid;
  const ZT* zp = zq + (long long)b * Dd * Nn + n;
  float dots[Kk];
  #pragma unroll
  for (int k = 0; k < Kk; ++k) dots[k] = 0.f;
  float xx = 0.f;
  for (int d = 0; d < Dd; ++d) {
    float xv = b2fOrF(zp[(long long)d * Nn]);
    xx = fmaf(xv, xv, xx);
    #pragma unroll
    for (int k = 0; k < Kk; ++k) dots[k] = fmaf(csm[k][d], xv, dots[k]);
  }
  float mx = -1e30f;
  #pragma unroll
  for (int k = 0; k < Kk; ++k) {
    float l = ssm[k] * (xx - 2.f * dots[k] + cc[k]);
    dots[k] = l;
    mx = fmaxf(mx, l);
  }
  float sum = 0.f;
  #pragma unroll
  for (int k = 0; k < Kk; ++k) { float p = expf(dots[k] - mx); dots[k] = p; sum += p; }
  float inv = 1.f / sum;
  #pragma unroll
  for (int k = 0; k < Kk; ++k) sA[k][tid] = dots[k] * inv;
  __syncthreads();
  if (tid < Kk) {
    float s = 0.f;
    for (int p = 0; p < 256; ++p) s += sA[tid][p];
    atomicAdd(&Asum[b * Kk + tid], s);
  }

  float acc[16];
  #pragma unroll
  for (int j = 0; j < 16; ++j) acc[j] = 0.f;
  const int k = tid & 31, d0 = (tid >> 5) * 16;
  const int ldd = tid >> 1, lpx = (tid & 1) * 8;
  for (int it = 0; it < 16; ++it) {
    __syncthreads();
    {
      const ZT* src = zq + ((long long)b * Dd + ldd) * Nn + n0 + it * 16 + lpx;
      float4 a4 = load4(src);
      float4 b4 = load4(src + 4);
      zs[ldd][lpx + 0] = a4.x; zs[ldd][lpx + 1] = a4.y;
      zs[ldd][lpx + 2] = a4.z; zs[ldd][lpx + 3] = a4.w;
      zs[ldd][lpx + 4] = b4.x; zs[ldd][lpx + 5] = b4.y;
      zs[ldd][lpx + 6] = b4.z; zs[ldd][lpx + 7] = b4.w;
    }
    __syncthreads();
    #pragma unroll
    for (int p = 0; p < 16; ++p) {
      float a = sA[k][it * 16 + p];
      #pragma unroll
      for (int j = 0; j < 16; ++j) acc[j] = fmaf(a, zs[d0 + j][p], acc[j]);
    }
  }
  float* Ep = Eraw + ((long long)b * Kk + k) * Dd + d0;
  #pragma unroll
  for (int j = 0; j < 16; ++j) atomicAdd(Ep + j, acc[j]);
}

__global__ __launch_bounds__(256) void bn_kernel(const float* __restrict__ Eraw,
    const float* __restrict__ Asum, const float* __restrict__ cw, float* __restrict__ Es) {
  int k = blockIdx.x, tid = threadIdx.x;
  float vals[4], s = 0.f, s2 = 0.f;
  #pragma unroll
  for (int r = 0; r < 4; ++r) {
    int i = r * 256 + tid;
    int b = i >> 7, d = i & 127;
    float e = Eraw[((long long)b * Kk + k) * Dd + d] - Asum[b * Kk + k] * cw[k * Dd + d];
    vals[r] = e; s += e; s2 = fmaf(e, e, s2);
  }
  s = blockSum256(s);
  s2 = blockSum256(s2);
  float mean = s * (1.f / 1024.f);
  float var = fmaxf(s2 * (1.f / 1024.f) - mean * mean, 0.f);
  float rs = rsqrtf(var + 1e-5f);
  #pragma unroll
  for (int r = 0; r < 4; ++r) {
    int i = r * 256 + tid;
    int b = i >> 7, d = i & 127;
    float e = (vals[r] - mean) * rs;
    if (e > 0.f) atomicAdd(&Es[b * Dd + d], e);
  }
}

__global__ __launch_bounds__(256) void gamma_kernel(const float* __restrict__ Es,
    const float* __restrict__ Wfc, const float* __restrict__ bfc, float* __restrict__ gam) {
  int gi = blockIdx.x * 256 + threadIdx.x;
  int b = gi >> 9, c = gi & 511;
  __shared__ float esm[Dd];
  if (threadIdx.x < Dd) esm[threadIdx.x] = Es[b * Dd + threadIdx.x];
  __syncthreads();
  const float* wr = Wfc + c * Dd;
  float acc = bfc[c];
  for (int d = 0; d < Dd; ++d) acc = fmaf(wr[d], esm[d], acc);
  gam[gi] = 1.f / (1.f + expf(-acc));
}

__global__ __launch_bounds__(256) void scaleout_f32(float* __restrict__ out,
    const float* __restrict__ gam) {
  unsigned int idx = blockIdx.x * 256u + threadIdx.x;
  unsigned int f = idx * 4u;
  unsigned int bc = f / (unsigned)Nn;
  float g = gam[bc];
  float4 zv = *(const float4*)(out + f);
  store4(out + f, zv.x * g, zv.y * g, zv.z * g, zv.w * g);
}

// ---------------- host launcher ----------------
extern "C" void kernel_launch(void* const* d_in, const int* in_sizes, int n_in,
                              void* d_out, int out_size, void* d_ws, size_t ws_size,
                              hipStream_t stream) {
  const float* X   = (const float*)d_in[0];
  const float* Wth = (const float*)d_in[1];
  const float* bth = (const float*)d_in[2];
  const float* Wph = (const float*)d_in[3];
  const float* bph = (const float*)d_in[4];
  const float* Wg  = (const float*)d_in[5];
  const float* bg  = (const float*)d_in[6];
  const float* W2  = (const float*)d_in[7];
  const float* b2v = (const float*)d_in[8];
  const float* W3  = (const float*)d_in[9];
  const float* b3v = (const float*)d_in[10];
  const float* CW  = (const float*)d_in[11];
  const float* SC  = (const float*)d_in[12];
  const float* Wfc = (const float*)d_in[13];
  const float* bfc = (const float*)d_in[14];
  float* out = (float*)d_out;
  float* wsf = (float*)d_ws;

  const long long szL   = (long long)Bb * C1 * C1;   // 524288
  const long long szRA  = (long long)Bb * Cc * Cc;   // 2097152
  const long long szRB  = (long long)Bb * C1 * Cc;   // 1048576
  long long off = 0;
  float* s_   = wsf + off; off += Bb * Cc;
  float* u_   = wsf + off; off += Bb * C1;
  float* v_   = wsf + off; off += Bb * C1;
  float* w_   = wsf + off; off += Bb * C1;
  float* q_   = wsf + off; off += Bb * Cc;
  float* Eraw_= wsf + off; off += (long long)Bb * Kk * Dd;
  float* Es_  = wsf + off; off += Bb * Dd;
  float* Asum_= wsf + off; off += Bb * Kk;
  float* gam_ = wsf + off; off += Bb * Cc;
  float* L_   = wsf + off; off += szL;
  float* regA = wsf + off; off += szRA;
  float* regB = wsf + off; off += szRB;
  const long long baseFloats = off;
  // tail region: T (batch-grouped), later aliased by zq
  float* tail = wsf + off;
  const long long T_STR = (long long)C1 * Nn;           // 2359296 floats per batch
  const long long ZQ_F  = (long long)Bb * Dd * Nn;      // 9437184
  const long long tailFloats = (long long)(ws_size / 4) - baseFloats;
  const bool big = tailFloats >= ZQ_F;    // 37.7 MB tail: T groups of 4 + fp32 zq
  const int grp = big ? 4 : 2;            // else: T groups of 2 + bf16 zq
  float* Tbuf = tail;
  float* zqf  = tail;
  u16*   zqh  = (u16*)tail;
  float* R_   = L_;    // alias: f dead after Mm-GEMM; R born after P-GEMM
  float* zqb_ = u_;    // alias: u dead after softmax

  const long long strX = (long long)Cc * Nn;
  const long long sG = (long long)Cc * Cc;
  const long long sU = (long long)C1 * Cc;
  const long long sL = (long long)C1 * C1;
  const long long sR = (long long)Dd * Cc;

  rowsum_kernel<<<Bb * Cc, 256, 0, stream>>>(X, s_, Nn);
  hipMemsetAsync(regB, 0, (size_t)szRB * 4, stream);  // U accumulates atomically
  for (int g = 0; g < Bb; g += grp) {
    // T = Wth @ X[g..g+grp)   (M=256, N=9216, K=512)
    gemm_mfma<float, 8, false, false><<<dim3(36 * 2 * grp), 256, 0, stream>>>(
        Wth, X + (long long)g * strX, Tbuf, Nn, Cc, 0, strX, T_STR,
        nullptr, 0, Cc, 1, 36, 2);
    // U += T @ X^T            (M=256, N=512, K=9216, split-K=8, atomic)
    gemm_mfma<float, 4, true, true><<<dim3(4 * 2 * grp * 8), 256, 0, stream>>>(
        Tbuf, X + (long long)g * strX, regB + (long long)g * sU, Cc, Nn,
        T_STR, strX, sU, nullptr, 0, Nn / 8, 8, 4, 2);
  }
  gemv512_kernel<<<Bb, 256, 0, stream>>>(Wth, s_, u_);
  gemv512_kernel<<<Bb, 256, 0, stream>>>(Wph, s_, v_);
  // L = U @ Wph^T
  gemm64<true><<<dim3(4, 4, Bb), 256, 0, stream>>>(
      regB, Wph, L_, C1, C1, Cc, sU, 0, sL, nullptr, 0);
  softmax_kernel<<<Bb * C1, 256, 0, stream>>>(L_, bth, bph, u_, v_);
  w_kernel<<<Bb, 256, 0, stream>>>(L_, bg, w_);
  // Mm = f @ Wg -> regB (U dead)
  gemm64<false><<<dim3(8, 4, Bb), 256, 0, stream>>>(
      L_, Wg, regB, C1, Cc, C1, sL, 0, sU, nullptr, 0);
  q_kernel<<<16, 256, 0, stream>>>(W2, b2v, w_, q_);
  // P = W2 @ Mm -> regA ; then P += I
  gemm64<false><<<dim3(8, 8, Bb), 256, 0, stream>>>(
      W2, regB, regA, Cc, Cc, C1, 0, sU, sG, nullptr, 0);
  adddiag_kernel<<<16, 256, 0, stream>>>(regA);
  // R = W3 @ P' -> R_ (alias L_) ; zq bias = W3 q + b3
  gemm64<false><<<dim3(8, 2, Bb), 256, 0, stream>>>(
      W3, regA, R_, Dd, Cc, Cc, 0, sG, sR, nullptr, 0);
  zqbias_kernel<<<4, 256, 0, stream>>>(W3, b3v, q_, zqb_);
  // z = P' @ X + q  -> out
  gemm_mfma<float, 8, false, false><<<dim3(1152), 256, 0, stream>>>(
      regA, X, out, Nn, Cc, sG, strX, strX, q_, Cc, Cc, 1, 36, 4);
  hipMemsetAsync(Eraw_, 0, (size_t)(Bb * Kk * Dd + Bb * Dd + Bb * Kk) * 4, stream);
  // zq = R @ X + zqb  (T dead -> tail reused)
  if (big) {
    gemm_mfma<float, 8, false, false><<<dim3(288), 256, 0, stream>>>(
        R_, X, zqf, Nn, Cc, sR, strX, (long long)Dd * Nn, zqb_, Dd, Cc, 1, 36, 1);
    enc_kernel<float><<<dim3(36, Bb), 256, 0, stream>>>(zqf, CW, SC, Eraw_, Asum_);
  } else {
    gemm_mfma<u16, 8, false, false><<<dim3(288), 256, 0, stream>>>(
        R_, X, zqh, Nn, Cc, sR, strX, (long long)Dd * Nn, zqb_, Dd, Cc, 1, 36, 1);
    enc_kernel<u16><<<dim3(36, Bb), 256, 0, stream>>>(zqh, CW, SC, Eraw_, Asum_);
  }
  bn_kernel<<<Kk, 256, 0, stream>>>(Eraw_, Asum_, CW, Es_);
  gamma_kernel<<<16, 256, 0, stream>>>(Es_, Wfc, bfc, gam_);
  const unsigned int n4 = (unsigned)(Bb * Cc * Nn / 4);
  scaleout_f32<<<n4 / 256, 256, 0, stream>>>(out, gam_);
  (void)in_sizes; (void)n_in; (void)out_size;
}

// Round 4
// 1098.891 us; speedup vs baseline: 1.7659x; 1.0191x over previous
//
#include <hip/hip_runtime.h>

// NLCE: non-local (channel attention) + Deep-TEN encoding, B=8 C=512 C1=256 D=128 K=32 N=9216.
// All inputs/outputs fp32. Big GEMMs on matrix cores via 2-limb bf16 split
// (hi/lo via v_cvt_pk_bf16_f32; products hi*hi+hi*lo+lo*hi, ~1e-5 rel).
// Algebra: G = X X^T (symmetric: upper-triangle tile-pairs only, split-K partials,
//          no atomics); U = Wth G; z = (W2 f Wg + I) X + q 1^T;
//          zq = (W3 (P+I)) X + (W3 q + b3).
// [Re-run of round-3 candidate: previous bench died at container level, no data.]

typedef unsigned short u16;

#define Bb 8
#define Cc 512
#define C1 256
#define Dd 128
#define Kk 32
#define Nn 9216

typedef __attribute__((ext_vector_type(8))) short short8v;
typedef __attribute__((ext_vector_type(4))) short short4v;
typedef __attribute__((ext_vector_type(4))) float f32x4;

__device__ __forceinline__ float b2f(u16 u) {
  union { unsigned int i; float f; } v; v.i = ((unsigned int)u) << 16; return v.f;
}
__device__ __forceinline__ u16 f2b(float f) {
  union { float f; unsigned int i; } v; v.f = f;
  unsigned int x = v.i;
  return (u16)((x + 0x7fffu + ((x >> 16) & 1u)) >> 16);  // RNE
}

__device__ __forceinline__ float b2fOrF(float x) { return x; }
__device__ __forceinline__ float b2fOrF(u16 x) { return b2f(x); }

__device__ __forceinline__ float4 load4(const float* p) { return *(const float4*)p; }
__device__ __forceinline__ float4 load4(const u16* p) {
  ushort4 q = *(const ushort4*)p;
  return make_float4(b2f(q.x), b2f(q.y), b2f(q.z), b2f(q.w));
}
__device__ __forceinline__ void store4(float* p, float a, float b, float c, float d) {
  *(float4*)p = make_float4(a, b, c, d);
}

__device__ __forceinline__ float waveSum(float v) {
  #pragma unroll
  for (int o = 32; o > 0; o >>= 1) v += __shfl_xor(v, o);
  return v;
}
__device__ __forceinline__ float waveMax(float v) {
  #pragma unroll
  for (int o = 32; o > 0; o >>= 1) v = fmaxf(v, __shfl_xor(v, o));
  return v;
}
__device__ __forceinline__ float blockSum256(float v) {
  __shared__ float sm[4];
  v = waveSum(v);
  if ((threadIdx.x & 63) == 0) sm[threadIdx.x >> 6] = v;
  __syncthreads();
  float r = sm[0] + sm[1] + sm[2] + sm[3];
  __syncthreads();
  return r;
}
__device__ __forceinline__ float blockMax256(float v) {
  __shared__ float sm[4];
  v = waveMax(v);
  if ((threadIdx.x & 63) == 0) sm[threadIdx.x >> 6] = v;
  __syncthreads();
  float r = fmaxf(fmaxf(sm[0], sm[1]), fmaxf(sm[2], sm[3]));
  __syncthreads();
  return r;
}

// ---------------- MFMA split-bf16 common ----------------
__device__ __forceinline__ f32x4 mfma_bf16_16x16x32(short8v a, short8v b, f32x4 c) {
  asm("v_mfma_f32_16x16x32_bf16 %0, %1, %2, %0" : "+v"(c) : "v"(a), "v"(b));
  return c;
}

__device__ __forceinline__ int fsw(int r) { return (r ^ (r >> 2) ^ (r >> 4)) & 3; }

// 2 floats -> packed bf16 hi limbs (h) and lo limbs (l), 1 cvt_pk each + exact residual
__device__ __forceinline__ void cvt2(float x0, float x1, unsigned int& h, unsigned int& l) {
  asm("v_cvt_pk_bf16_f32 %0, %1, %2" : "=v"(h) : "v"(x0), "v"(x1));
  union { unsigned int u; float f; } fa, fb;
  fa.u = h << 16; fb.u = h & 0xffff0000u;
  float r0 = x0 - fa.f, r1 = x1 - fb.f;
  asm("v_cvt_pk_bf16_f32 %0, %1, %2" : "=v"(l) : "v"(r0), "v"(r1));
}

__device__ __forceinline__ void storeC(float* p, float v) { *p = v; }
__device__ __forceinline__ void storeC(u16* p, float v) { *p = f2b(v); }

// ---------------- generic MFMA GEMM (z / zq) ----------------
// C[b] = A[b] @ B[b] (+ biasRow per-M) ; fp32 in, TO out, 2-limb bf16 MFMA inside.
// BM = 128, BN = 32*NF, BK = 32. 256 threads = 4 waves (2x2), wave tile 64 x (16*NF).
template<typename TO, int NF>
__global__ __launch_bounds__(256, 2) void gemm_mfma(
    const float* __restrict__ A, const float* __restrict__ B, TO* __restrict__ C,
    int N, int K,
    long long sA, long long sB, long long sC,
    const float* __restrict__ biasRow, long long sBias,
    int gnx, int gny)
{
  static_assert(NF == 4 || NF == 8, "NF");
  constexpr int BN = 32 * NF;
  // element (row,k) stored at column ((k>>3) ^ fsw(row))*8 + (k&7); stride 40 ushorts.
  __shared__ __align__(16) u16 Asm_[2][128][40];
  __shared__ __align__(16) u16 Bsm_[2][BN][40];

  int id = blockIdx.x;
  {
    const int nwg = gridDim.x;
    if ((nwg & 7) == 0) id = (id & 7) * (nwg >> 3) + (id >> 3);  // XCD chunk swizzle
  }
  const int per = gnx * gny;
  const int b = id / per;
  const int rem = id - b * per;
  const int by = rem % gny;        // m-block fastest
  const int bx = rem / gny;        // n-block
  A += b * sA; B += b * sB; C += b * sC;
  const int m0 = by * 128, n0 = bx * BN;

  const int t = threadIdx.x;
  const int w = t >> 6, lane = t & 63;
  const int wr = w >> 1, wc = w & 1;
  const int lr = lane & 15, lq = lane >> 4;

  const int sar = t >> 1, sak = (t & 1) * 16;   // A staging map
  const int kg = t >> 5, ng = t & 31;           // B staging map

  float ra[16];
  float rb[32];

  auto loadA = [&](int k0) {
    const float* p = A + (long long)(m0 + sar) * K + (k0 + sak);
    #pragma unroll
    for (int i = 0; i < 4; ++i) {
      float4 v = *(const float4*)(p + i * 4);
      ra[i*4+0] = v.x; ra[i*4+1] = v.y; ra[i*4+2] = v.z; ra[i*4+3] = v.w;
    }
  };
  auto loadB = [&](int k0) {
    const float* p = B + (long long)(k0 + kg * 4) * N + (n0 + ng * 8);
    #pragma unroll
    for (int i = 0; i < 4; ++i) {
      float4 v0 = *(const float4*)(p + (long long)i * N);
      float4 v1 = *(const float4*)(p + (long long)i * N + 4);
      rb[i*8+0]=v0.x; rb[i*8+1]=v0.y; rb[i*8+2]=v0.z; rb[i*8+3]=v0.w;
      rb[i*8+4]=v1.x; rb[i*8+5]=v1.y; rb[i*8+6]=v1.z; rb[i*8+7]=v1.w;
    }
  };

  auto stage = [&]() {
    {   // A rows sar, k-local sak..sak+15 -> two swizzled 8-blocks
      const int f = fsw(sar);
      #pragma unroll
      for (int h = 0; h < 2; ++h) {
        const int col = ((((sak >> 3) + h) ^ f) << 3);
        union { unsigned int u[4]; short8v v; } H, L;
        #pragma unroll
        for (int p = 0; p < 4; ++p) cvt2(ra[h*8+2*p], ra[h*8+2*p+1], H.u[p], L.u[p]);
        *(short8v*)&Asm_[0][sar][col] = H.v;
        *(short8v*)&Asm_[1][sar][col] = L.v;
      }
    }
    {   // transpose 4k x 8n block into n-major LDS, 4 consecutive k per b64 write
      #pragma unroll
      for (int j = 0; j < 8; ++j) {
        const int n = ng * 8 + j;
        const int col = (((kg >> 1) ^ fsw(n)) << 3) + (kg & 1) * 4;
        union { unsigned int u[2]; short4v v; } H, L;
        #pragma unroll
        for (int p = 0; p < 2; ++p)
          cvt2(rb[(2*p)*8 + j], rb[(2*p+1)*8 + j], H.u[p], L.u[p]);
        *(short4v*)&Bsm_[0][n][col] = H.v;
        *(short4v*)&Bsm_[1][n][col] = L.v;
      }
    }
  };

  f32x4 acc[4][NF];
  #pragma unroll
  for (int im = 0; im < 4; ++im)
    #pragma unroll
    for (int in = 0; in < NF; ++in)
      acc[im][in] = f32x4{0.f, 0.f, 0.f, 0.f};

  loadA(0); loadB(0);
  for (int k0 = 0; k0 < K; k0 += 32) {
    stage();
    if (k0 + 32 < K) { loadA(k0 + 32); loadB(k0 + 32); }
    __syncthreads();
    short8v af[2][4];
    #pragma unroll
    for (int im = 0; im < 4; ++im) {
      const int r = wr * 64 + im * 16 + lr;
      const int col = ((lq ^ fsw(r)) << 3);
      af[0][im] = *(const short8v*)&Asm_[0][r][col];
      af[1][im] = *(const short8v*)&Asm_[1][r][col];
    }
    #pragma unroll
    for (int in = 0; in < NF; ++in) {
      const int rB = wc * NF * 16 + in * 16 + lr;
      const int colB = ((lq ^ fsw(rB)) << 3);
      short8v bh = *(const short8v*)&Bsm_[0][rB][colB];
      short8v bl = *(const short8v*)&Bsm_[1][rB][colB];
      #pragma unroll
      for (int im = 0; im < 4; ++im) {
        acc[im][in] = mfma_bf16_16x16x32(af[0][im], bh, acc[im][in]);  // hi*hi
        acc[im][in] = mfma_bf16_16x16x32(af[0][im], bl, acc[im][in]);  // hi*lo
        acc[im][in] = mfma_bf16_16x16x32(af[1][im], bh, acc[im][in]);  // lo*hi
      }
    }
    __syncthreads();
  }
  asm volatile("s_nop 7\n\ts_nop 7\n\ts_nop 7");  // MFMA->VALU/VMEM read hazard guard

  #pragma unroll
  for (int im = 0; im < 4; ++im) {
    #pragma unroll
    for (int in = 0; in < NF; ++in) {
      const f32x4 a = acc[im][in];
      const int gc = n0 + wc * NF * 16 + in * 16 + lr;   // C/D: col = lane&15
      #pragma unroll
      for (int p = 0; p < 4; ++p) {
        const int gr = m0 + wr * 64 + im * 16 + lq * 4 + p;  // row = (lane>>4)*4+reg
        float v = a[p];
        if (biasRow) v += biasRow[b * sBias + gr];
        storeC(&C[(long long)gr * N + gc], v);
      }
    }
  }
}

// ---------------- G = X X^T, symmetric, split-K partials (no atomics) --------
// Upper-triangle 128x128 tile-pairs (10 per batch). Block = (pair, ks, b).
// part[(ks*Bb + b)*10 + pair][128][128] += X_b[i-tile] . X_b[j-tile]^T over k-chunk.
__device__ __constant__ int PIa[10] = {0,0,0,0,1,1,1,2,2,3};
__device__ __constant__ int PJa[10] = {0,1,2,3,1,2,3,2,3,3};

__global__ __launch_bounds__(256, 2) void gxxt_kernel(
    const float* __restrict__ X, float* __restrict__ part,
    int numKS, int kChunk)
{
  __shared__ __align__(16) u16 Asm_[2][128][40];
  __shared__ __align__(16) u16 Bsm_[2][128][40];

  int id = blockIdx.x;
  {
    const int nwg = gridDim.x;
    if ((nwg & 7) == 0) id = (id & 7) * (nwg >> 3) + (id >> 3);  // one batch per XCD
  }
  const int pair = id % 10;
  const int rest = id / 10;
  const int ks = rest % numKS;
  const int b = rest / numKS;
  const int i0 = PIa[pair] * 128, j0 = PJa[pair] * 128;
  const bool same = (i0 == j0);
  const float* Xb = X + (long long)b * Cc * Nn;
  const int kBeg = ks * kChunk, kEnd = kBeg + kChunk;

  const int t = threadIdx.x;
  const int w = t >> 6, lane = t & 63;
  const int wr = w >> 1, wc = w & 1;
  const int lr = lane & 15, lq = lane >> 4;
  const int sar = t >> 1, sak = (t & 1) * 16;

  float ra[16], rb[16];

  auto loadA = [&](int k0) {
    const float* p = Xb + (long long)(i0 + sar) * Nn + (k0 + sak);
    #pragma unroll
    for (int i = 0; i < 4; ++i) {
      float4 v = *(const float4*)(p + i * 4);
      ra[i*4+0] = v.x; ra[i*4+1] = v.y; ra[i*4+2] = v.z; ra[i*4+3] = v.w;
    }
  };
  auto loadB = [&](int k0) {
    const float* p = Xb + (long long)(j0 + sar) * Nn + (k0 + sak);
    #pragma unroll
    for (int i = 0; i < 4; ++i) {
      float4 v = *(const float4*)(p + i * 4);
      rb[i*4+0] = v.x; rb[i*4+1] = v.y; rb[i*4+2] = v.z; rb[i*4+3] = v.w;
    }
  };
  auto stageRow = [&](const float* s16, u16 (*H)[40], u16 (*L)[40]) {
    const int f = fsw(sar);
    #pragma unroll
    for (int h = 0; h < 2; ++h) {
      const int col = ((((sak >> 3) + h) ^ f) << 3);
      union { unsigned int u[4]; short8v v; } Hv, Lv;
      #pragma unroll
      for (int p = 0; p < 4; ++p) cvt2(s16[h*8+2*p], s16[h*8+2*p+1], Hv.u[p], Lv.u[p]);
      *(short8v*)&H[sar][col] = Hv.v;
      *(short8v*)&L[sar][col] = Lv.v;
    }
  };

  const u16 (*BH)[40] = same ? Asm_[0] : Bsm_[0];
  const u16 (*BL)[40] = same ? Asm_[1] : Bsm_[1];

  f32x4 acc[4][4];
  #pragma unroll
  for (int im = 0; im < 4; ++im)
    #pragma unroll
    for (int in = 0; in < 4; ++in)
      acc[im][in] = f32x4{0.f, 0.f, 0.f, 0.f};

  loadA(kBeg);
  if (!same) loadB(kBeg);
  for (int k0 = kBeg; k0 < kEnd; k0 += 32) {
    stageRow(ra, Asm_[0], Asm_[1]);
    if (!same) stageRow(rb, Bsm_[0], Bsm_[1]);
    if (k0 + 32 < kEnd) { loadA(k0 + 32); if (!same) loadB(k0 + 32); }
    __syncthreads();
    short8v af[2][4];
    #pragma unroll
    for (int im = 0; im < 4; ++im) {
      const int r = wr * 64 + im * 16 + lr;
      const int col = ((lq ^ fsw(r)) << 3);
      af[0][im] = *(const short8v*)&Asm_[0][r][col];
      af[1][im] = *(const short8v*)&Asm_[1][r][col];
    }
    #pragma unroll
    for (int in = 0; in < 4; ++in) {
      const int rB = wc * 64 + in * 16 + lr;
      const int colB = ((lq ^ fsw(rB)) << 3);
      short8v bh = *(const short8v*)&BH[rB][colB];
      short8v bl = *(const short8v*)&BL[rB][colB];
      #pragma unroll
      for (int im = 0; im < 4; ++im) {
        acc[im][in] = mfma_bf16_16x16x32(af[0][im], bh, acc[im][in]);
        acc[im][in] = mfma_bf16_16x16x32(af[0][im], bl, acc[im][in]);
        acc[im][in] = mfma_bf16_16x16x32(af[1][im], bh, acc[im][in]);
      }
    }
    __syncthreads();
  }
  asm volatile("s_nop 7\n\ts_nop 7\n\ts_nop 7");

  float* Cp = part + ((long long)(ks * Bb + b) * 10 + pair) * 16384;
  #pragma unroll
  for (int im = 0; im < 4; ++im) {
    #pragma unroll
    for (int in = 0; in < 4; ++in) {
      const f32x4 a = acc[im][in];
      const int gc = wc * 64 + in * 16 + lr;
      #pragma unroll
      for (int p = 0; p < 4; ++p) {
        const int gr = wr * 64 + im * 16 + lq * 4 + p;
        Cp[gr * 128 + gc] = a[p];
      }
    }
  }
}

// Reduce partials -> G (both triangles). One block per (b, pair).
__global__ __launch_bounds__(256) void gred_kernel(const float* __restrict__ part,
    float* __restrict__ G, int numKS) {
  __shared__ float sm[64][129];
  const int pair = blockIdx.x % 10, b = blockIdx.x / 10;
  const int i0 = PIa[pair] * 128, j0 = PJa[pair] * 128;
  float* Gb = G + (long long)b * Cc * Cc;
  const long long ksStr = (long long)Bb * 10 * 16384;
  const float* p0 = part + ((long long)b * 10 + pair) * 16384;
  const int t = threadIdx.x;
  for (int half = 0; half < 2; ++half) {
    const int r0 = half * 64;
    __syncthreads();
    for (int rep = 0; rep < 32; ++rep) {
      int idx = r0 * 128 + rep * 256 + t;
      float s = 0.f;
      for (int ks = 0; ks < numKS; ++ks) s += p0[(long long)ks * ksStr + idx];
      int r = (idx >> 7) - r0, c = idx & 127;
      sm[r][c] = s;
      Gb[(long long)(i0 + r0 + r) * Cc + (j0 + c)] = s;
    }
    if (i0 != j0) {
      __syncthreads();
      for (int rep = 0; rep < 32; ++rep) {
        int o = rep * 256 + t;
        int rr = o >> 6, cc = o & 63;
        Gb[(long long)(j0 + rr) * Cc + (i0 + r0 + cc)] = sm[cc][rr];
      }
    }
  }
}

// ---------------- generic 64x64 tiled GEMM, fp32 (small GEMMs) ----------------
template<bool TRANSB>
__global__ __launch_bounds__(256) void gemm64(
    const float* __restrict__ A, const float* __restrict__ B, float* __restrict__ C,
    int M, int N, int K,
    long long sA, long long sB, long long sC,
    const float* __restrict__ biasRow, long long sBias)
{
  const int bz = blockIdx.z;
  A += (long long)bz * sA;
  B += (long long)bz * sB;
  C += (long long)bz * sC;
  const int m0 = blockIdx.y * 64, n0 = blockIdx.x * 64;
  __shared__ __align__(16) float As[16][64];
  __shared__ __align__(16) float Bs[16][64];
  const int t = threadIdx.x;
  const int lr = t >> 2, lk = (t & 3) << 2;
  const int tm = (t >> 4) << 2, tn = (t & 15) << 2;
  float acc[4][4] = {};
  for (int k0 = 0; k0 < K; k0 += 16) {
    {
      float4 a = load4(A + (long long)(m0 + lr) * K + (k0 + lk));
      As[lk + 0][lr] = a.x; As[lk + 1][lr] = a.y; As[lk + 2][lr] = a.z; As[lk + 3][lr] = a.w;
    }
    if (TRANSB) {
      float4 b = load4(B + (long long)(n0 + lr) * K + (k0 + lk));
      Bs[lk + 0][lr] = b.x; Bs[lk + 1][lr] = b.y; Bs[lk + 2][lr] = b.z; Bs[lk + 3][lr] = b.w;
    } else {
      const int kr = t >> 4, nc = (t & 15) << 2;
      float4 b = load4(B + (long long)(k0 + kr) * N + (n0 + nc));
      *(float4*)&Bs[kr][nc] = b;
    }
    __syncthreads();
    #pragma unroll
    for (int kk = 0; kk < 16; ++kk) {
      const float4 av = *(const float4*)&As[kk][tm];
      const float4 bv = *(const float4*)&Bs[kk][tn];
      acc[0][0] = fmaf(av.x, bv.x, acc[0][0]);
      acc[0][1] = fmaf(av.x, bv.y, acc[0][1]);
      acc[0][2] = fmaf(av.x, bv.z, acc[0][2]);
      acc[0][3] = fmaf(av.x, bv.w, acc[0][3]);
      acc[1][0] = fmaf(av.y, bv.x, acc[1][0]);
      acc[1][1] = fmaf(av.y, bv.y, acc[1][1]);
      acc[1][2] = fmaf(av.y, bv.z, acc[1][2]);
      acc[1][3] = fmaf(av.y, bv.w, acc[1][3]);
      acc[2][0] = fmaf(av.z, bv.x, acc[2][0]);
      acc[2][1] = fmaf(av.z, bv.y, acc[2][1]);
      acc[2][2] = fmaf(av.z, bv.z, acc[2][2]);
      acc[2][3] = fmaf(av.z, bv.w, acc[2][3]);
      acc[3][0] = fmaf(av.w, bv.x, acc[3][0]);
      acc[3][1] = fmaf(av.w, bv.y, acc[3][1]);
      acc[3][2] = fmaf(av.w, bv.z, acc[3][2]);
      acc[3][3] = fmaf(av.w, bv.w, acc[3][3]);
    }
    __syncthreads();
  }
  #pragma unroll
  for (int i = 0; i < 4; ++i) {
    const int m = m0 + tm + i;
    float bias = biasRow ? biasRow[bz * sBias + m] : 0.f;
    store4(C + (long long)m * N + (n0 + tn),
           acc[i][0] + bias, acc[i][1] + bias, acc[i][2] + bias, acc[i][3] + bias);
  }
}

// ---------------- small kernels ----------------
__global__ __launch_bounds__(256) void rowsum_kernel(const float* __restrict__ X,
                                                     float* __restrict__ s, int N) {
  long long row = blockIdx.x;
  const float* p = X + row * N;
  float acc = 0.f;
  for (int i = threadIdx.x; i < N; i += 256) acc += p[i];
  acc = blockSum256(acc);
  if (threadIdx.x == 0) s[row] = acc;
}

__global__ __launch_bounds__(256) void gemv512_kernel(const float* __restrict__ W,
                                                      const float* __restrict__ s,
                                                      float* __restrict__ out) {
  int b = blockIdx.x;
  __shared__ float ssm[Cc];
  for (int i = threadIdx.x; i < Cc; i += 256) ssm[i] = s[b * Cc + i];
  __syncthreads();
  int i = threadIdx.x;
  const float* wr = W + i * Cc;
  float acc = 0.f;
  for (int k = 0; k < Cc; ++k) acc = fmaf(wr[k], ssm[k], acc);
  out[b * C1 + i] = acc;
}

__global__ __launch_bounds__(256) void softmax_kernel(float* __restrict__ L,
    const float* __restrict__ bth, const float* __restrict__ bph,
    const float* __restrict__ u, const float* __restrict__ v) {
  int row = blockIdx.x;                 // b*256 + i
  int b = row >> 8, i = row & 255;
  int j = threadIdx.x;
  float bt = bth[i], bp = bph[j];
  long long idx = (long long)row * C1 + j;
  float val = L[idx] + bt * v[b * C1 + j] + u[b * C1 + i] * bp + (float)Nn * bt * bp;
  float mx = blockMax256(val);
  float p = expf(val - mx);
  float sm = blockSum256(p);
  L[idx] = p / sm;
}

__global__ __launch_bounds__(256) void w_kernel(const float* __restrict__ f,
                                                const float* __restrict__ bg,
                                                float* __restrict__ w) {
  int b = blockIdx.x;
  __shared__ float bgs[C1];
  bgs[threadIdx.x] = bg[threadIdx.x];
  __syncthreads();
  int i = threadIdx.x;
  const float* fr = f + ((long long)b * C1 + i) * C1;
  float acc = 0.f;
  for (int j = 0; j < C1; ++j) acc = fmaf(fr[j], bgs[j], acc);
  w[b * C1 + i] = acc;
}

__global__ __launch_bounds__(256) void q_kernel(const float* __restrict__ W2,
                                                const float* __restrict__ b2v,
                                                const float* __restrict__ w,
                                                float* __restrict__ q) {
  int gi = blockIdx.x * 256 + threadIdx.x;
  int b = gi >> 9, c = gi & 511;
  __shared__ float wsm[C1];
  wsm[threadIdx.x] = w[b * C1 + threadIdx.x];
  __syncthreads();
  const float* wr = W2 + c * C1;
  float acc = b2v[c];
  for (int i = 0; i < C1; ++i) acc = fmaf(wr[i], wsm[i], acc);
  q[gi] = acc;
}

// P[b] += I  (fold the residual connection into the GEMM operand)
__global__ __launch_bounds__(256) void adddiag_kernel(float* __restrict__ P) {
  int gi = blockIdx.x * 256 + threadIdx.x;   // [0, 8*512)
  int b = gi >> 9, c = gi & 511;
  P[((long long)b * Cc + c) * Cc + c] += 1.f;
}

// zqb[b][d] = b3[d] + sum_c W3[d][c] * q[b][c]
__global__ __launch_bounds__(256) void zqbias_kernel(const float* __restrict__ W3,
    const float* __restrict__ b3, const float* __restrict__ q, float* __restrict__ zqb) {
  int gi = blockIdx.x * 256 + threadIdx.x;   // [0, 1024)
  int b = gi >> 7, d = gi & 127;
  const float* wr = W3 + d * Cc;
  const float* qr = q + b * Cc;
  float acc = b3[d];
  for (int c = 0; c < Cc; ++c) acc = fmaf(wr[c], qr[c], acc);
  zqb[gi] = acc;
}

template<typename ZT>
__global__ __launch_bounds__(256) void enc_kernel(
    const ZT* __restrict__ zq,      // [B][D][N]
    const float* __restrict__ cw,   // [K][D]
    const float* __restrict__ sc,   // [K]
    float* __restrict__ Eraw,       // [B][K][D] pre-zeroed
    float* __restrict__ Asum)       // [B][K]    pre-zeroed
{
  __shared__ float csm[Kk][Dd + 1];
  __shared__ float cc[Kk], ssm[Kk];
  __shared__ float sA[Kk][256 + 1];
  __shared__ float zs[Dd][17];
  const int tid = threadIdx.x;
  const int b = blockIdx.y;
  const int n0 = blockIdx.x * 256;

  #pragma unroll
  for (int r = 0; r < 16; ++r) {
    int idx = r * 256 + tid;
    csm[idx >> 7][idx & 127] = cw[idx];
  }
  if (tid < Kk) ssm[tid] = sc[tid];
  __syncthreads();
  if (tid < Kk) {
    float a = 0.f;
    for (int d = 0; d < Dd; ++d) { float cv = csm[tid][d]; a = fmaf(cv, cv, a); }
    cc[tid] = a;
  }
  __syncthreads();

  const int n = n0 + tid;
  const ZT* zp = zq + (long long)b * Dd * Nn + n;
  float dots[Kk];
  #pragma unroll
  for (int k = 0; k < Kk; ++k) dots[k] = 0.f;
  float xx = 0.f;
  for (int d = 0; d < Dd; ++d) {
    float xv = b2fOrF(zp[(long long)d * Nn]);
    xx = fmaf(xv, xv, xx);
    #pragma unroll
    for (int k = 0; k < Kk; ++k) dots[k] = fmaf(csm[k][d], xv, dots[k]);
  }
  float mx = -1e30f;
  #pragma unroll
  for (int k = 0; k < Kk; ++k) {
    float l = ssm[k] * (xx - 2.f * dots[k] + cc[k]);
    dots[k] = l;
    mx = fmaxf(mx, l);
  }
  float sum = 0.f;
  #pragma unroll
  for (int k = 0; k < Kk; ++k) { float p = expf(dots[k] - mx); dots[k] = p; sum += p; }
  float inv = 1.f / sum;
  #pragma unroll
  for (int k = 0; k < Kk; ++k) sA[k][tid] = dots[k] * inv;
  __syncthreads();
  if (tid < Kk) {
    float s = 0.f;
    for (int p = 0; p < 256; ++p) s += sA[tid][p];
    atomicAdd(&Asum[b * Kk + tid], s);
  }

  float acc[16];
  #pragma unroll
  for (int j = 0; j < 16; ++j) acc[j] = 0.f;
  const int k = tid & 31, d0 = (tid >> 5) * 16;
  const int ldd = tid >> 1, lpx = (tid & 1) * 8;
  for (int it = 0; it < 16; ++it) {
    __syncthreads();
    {
      const ZT* src = zq + ((long long)b * Dd + ldd) * Nn + n0 + it * 16 + lpx;
      float4 a4 = load4(src);
      float4 b4 = load4(src + 4);
      zs[ldd][lpx + 0] = a4.x; zs[ldd][lpx + 1] = a4.y;
      zs[ldd][lpx + 2] = a4.z; zs[ldd][lpx + 3] = a4.w;
      zs[ldd][lpx + 4] = b4.x; zs[ldd][lpx + 5] = b4.y;
      zs[ldd][lpx + 6] = b4.z; zs[ldd][lpx + 7] = b4.w;
    }
    __syncthreads();
    #pragma unroll
    for (int p = 0; p < 16; ++p) {
      float a = sA[k][it * 16 + p];
      #pragma unroll
      for (int j = 0; j < 16; ++j) acc[j] = fmaf(a, zs[d0 + j][p], acc[j]);
    }
  }
  float* Ep = Eraw + ((long long)b * Kk + k) * Dd + d0;
  #pragma unroll
  for (int j = 0; j < 16; ++j) atomicAdd(Ep + j, acc[j]);
}

__global__ __launch_bounds__(256) void bn_kernel(const float* __restrict__ Eraw,
    const float* __restrict__ Asum, const float* __restrict__ cw, float* __restrict__ Es) {
  int k = blockIdx.x, tid = threadIdx.x;
  float vals[4], s = 0.f, s2 = 0.f;
  #pragma unroll
  for (int r = 0; r < 4; ++r) {
    int i = r * 256 + tid;
    int b = i >> 7, d = i & 127;
    float e = Eraw[((long long)b * Kk + k) * Dd + d] - Asum[b * Kk + k] * cw[k * Dd + d];
    vals[r] = e; s += e; s2 = fmaf(e, e, s2);
  }
  s = blockSum256(s);
  s2 = blockSum256(s2);
  float mean = s * (1.f / 1024.f);
  float var = fmaxf(s2 * (1.f / 1024.f) - mean * mean, 0.f);
  float rs = rsqrtf(var + 1e-5f);
  #pragma unroll
  for (int r = 0; r < 4; ++r) {
    int i = r * 256 + tid;
    int b = i >> 7, d = i & 127;
    float e = (vals[r] - mean) * rs;
    if (e > 0.f) atomicAdd(&Es[b * Dd + d], e);
  }
}

__global__ __launch_bounds__(256) void gamma_kernel(const float* __restrict__ Es,
    const float* __restrict__ Wfc, const float* __restrict__ bfc, float* __restrict__ gam) {
  int gi = blockIdx.x * 256 + threadIdx.x;
  int b = gi >> 9, c = gi & 511;
  __shared__ float esm[Dd];
  if (threadIdx.x < Dd) esm[threadIdx.x] = Es[b * Dd + threadIdx.x];
  __syncthreads();
  const float* wr = Wfc + c * Dd;
  float acc = bfc[c];
  for (int d = 0; d < Dd; ++d) acc = fmaf(wr[d], esm[d], acc);
  gam[gi] = 1.f / (1.f + expf(-acc));
}

__global__ __launch_bounds__(256) void scaleout_f32(float* __restrict__ out,
    const float* __restrict__ gam) {
  unsigned int idx = blockIdx.x * 256u + threadIdx.x;
  unsigned int f = idx * 4u;
  unsigned int bc = f / (unsigned)Nn;
  float g = gam[bc];
  float4 zv = *(const float4*)(out + f);
  store4(out + f, zv.x * g, zv.y * g, zv.z * g, zv.w * g);
}

// ---------------- host launcher ----------------
extern "C" void kernel_launch(void* const* d_in, const int* in_sizes, int n_in,
                              void* d_out, int out_size, void* d_ws, size_t ws_size,
                              hipStream_t stream) {
  const float* X   = (const float*)d_in[0];
  const float* Wth = (const float*)d_in[1];
  const float* bth = (const float*)d_in[2];
  const float* Wph = (const float*)d_in[3];
  const float* bph = (const float*)d_in[4];
  const float* Wg  = (const float*)d_in[5];
  const float* bg  = (const float*)d_in[6];
  const float* W2  = (const float*)d_in[7];
  const float* b2v = (const float*)d_in[8];
  const float* W3  = (const float*)d_in[9];
  const float* b3v = (const float*)d_in[10];
  const float* CW  = (const float*)d_in[11];
  const float* SC  = (const float*)d_in[12];
  const float* Wfc = (const float*)d_in[13];
  const float* bfc = (const float*)d_in[14];
  float* out = (float*)d_out;
  float* wsf = (float*)d_ws;

  const long long szL   = (long long)Bb * C1 * C1;   // 524288
  const long long szRA  = (long long)Bb * Cc * Cc;   // 2097152
  const long long szRB  = (long long)Bb * C1 * Cc;   // 1048576
  long long off = 0;
  float* s_   = wsf + off; off += Bb * Cc;
  float* u_   = wsf + off; off += Bb * C1;
  float* v_   = wsf + off; off += Bb * C1;
  float* w_   = wsf + off; off += Bb * C1;
  float* q_   = wsf + off; off += Bb * Cc;
  float* Eraw_= wsf + off; off += (long long)Bb * Kk * Dd;
  float* Es_  = wsf + off; off += Bb * Dd;
  float* Asum_= wsf + off; off += Bb * Kk;
  float* gam_ = wsf + off; off += Bb * Cc;
  float* L_   = wsf + off; off += szL;
  float* regA = wsf + off; off += szRA;
  float* regB = wsf + off; off += szRB;
  const long long baseFloats = off;
  // tail region: G split-K partials, later aliased by zq
  float* tail = wsf + off;
  const long long ZQ_F  = (long long)Bb * Dd * Nn;      // 9437184
  const long long tailFloats = (long long)(ws_size / 4) - baseFloats;
  const bool big = tailFloats >= ZQ_F;    // big: fp32 zq + splitK=6; small: bf16 zq + splitK=2
  const int numKS = big ? 6 : 2;          // partials: numKS*8*10*16384 floats (7.9M / 2.6M)
  float* part = tail;
  float* zqf  = tail;
  u16*   zqh  = (u16*)tail;
  float* R_   = L_;    // alias: f dead after Mm-GEMM; R born after P-GEMM
  float* zqb_ = u_;    // alias: u dead after softmax

  const long long strX = (long long)Cc * Nn;
  const long long sG = (long long)Cc * Cc;
  const long long sU = (long long)C1 * Cc;
  const long long sL = (long long)C1 * C1;
  const long long sR = (long long)Dd * Cc;

  rowsum_kernel<<<Bb * Cc, 256, 0, stream>>>(X, s_, Nn);
  // G = X X^T (symmetric): tile-pair partials -> reduce into regA
  gxxt_kernel<<<dim3(10 * numKS * Bb), 256, 0, stream>>>(X, part, numKS, Nn / numKS);
  gred_kernel<<<dim3(10 * Bb), 256, 0, stream>>>(part, regA, numKS);
  // U = Wth @ G -> regB
  gemm64<false><<<dim3(8, 4, Bb), 256, 0, stream>>>(
      Wth, regA, regB, C1, Cc, Cc, 0, sG, sU, nullptr, 0);
  gemv512_kernel<<<Bb, 256, 0, stream>>>(Wth, s_, u_);
  gemv512_kernel<<<Bb, 256, 0, stream>>>(Wph, s_, v_);
  // L = U @ Wph^T
  gemm64<true><<<dim3(4, 4, Bb), 256, 0, stream>>>(
      regB, Wph, L_, C1, C1, Cc, sU, 0, sL, nullptr, 0);
  softmax_kernel<<<Bb * C1, 256, 0, stream>>>(L_, bth, bph, u_, v_);
  w_kernel<<<Bb, 256, 0, stream>>>(L_, bg, w_);
  // Mm = f @ Wg -> regB (U dead)
  gemm64<false><<<dim3(8, 4, Bb), 256, 0, stream>>>(
      L_, Wg, regB, C1, Cc, C1, sL, 0, sU, nullptr, 0);
  q_kernel<<<16, 256, 0, stream>>>(W2, b2v, w_, q_);
  // P = W2 @ Mm -> regA (G dead) ; then P += I
  gemm64<false><<<dim3(8, 8, Bb), 256, 0, stream>>>(
      W2, regB, regA, Cc, Cc, C1, 0, sU, sG, nullptr, 0);
  adddiag_kernel<<<16, 256, 0, stream>>>(regA);
  // R = W3 @ P' -> R_ (alias L_) ; zq bias = W3 q + b3
  gemm64<false><<<dim3(8, 2, Bb), 256, 0, stream>>>(
      W3, regA, R_, Dd, Cc, Cc, 0, sG, sR, nullptr, 0);
  zqbias_kernel<<<4, 256, 0, stream>>>(W3, b3v, q_, zqb_);
  // z = P' @ X + q  -> out
  gemm_mfma<float, 8><<<dim3(1152), 256, 0, stream>>>(
      regA, X, out, Nn, Cc, sG, strX, strX, q_, Cc, 36, 4);
  hipMemsetAsync(Eraw_, 0, (size_t)(Bb * Kk * Dd + Bb * Dd + Bb * Kk) * 4, stream);
  // zq = R @ X + zqb  (partials dead -> tail reused)
  if (big) {
    gemm_mfma<float, 8><<<dim3(288), 256, 0, stream>>>(
        R_, X, zqf, Nn, Cc, sR, strX, (long long)Dd * Nn, zqb_, Dd, 36, 1);
    enc_kernel<float><<<dim3(36, Bb), 256, 0, stream>>>(zqf, CW, SC, Eraw_, Asum_);
  } else {
    gemm_mfma<u16, 8><<<dim3(288), 256, 0, stream>>>(
        R_, X, zqh, Nn, Cc, sR, strX, (long long)Dd * Nn, zqb_, Dd, 36, 1);
    enc_kernel<u16><<<dim3(36, Bb), 256, 0, stream>>>(zqh, CW, SC, Eraw_, Asum_);
  }
  bn_kernel<<<Kk, 256, 0, stream>>>(Eraw_, Asum_, CW, Es_);
  gamma_kernel<<<16, 256, 0, stream>>>(Es_, Wfc, bfc, gam_);
  const unsigned int n4 = (unsigned)(Bb * Cc * Nn / 4);
  scaleout_f32<<<n4 / 256, 256, 0, stream>>>(out, gam_);
  (void)in_sizes; (void)n_in; (void)out_size;
}

// Round 5
// 1095.844 us; speedup vs baseline: 1.7708x; 1.0028x over previous
//
#include <hip/hip_runtime.h>

// NLCE: non-local (channel attention) + Deep-TEN encoding, B=8 C=512 C1=256 D=128 K=32 N=9216.
// All inputs/outputs fp32. Big GEMMs on matrix cores via 2-limb bf16 split
// (hi/lo via v_cvt_pk_bf16_f32; products hi*hi+hi*lo+lo*hi, ~1e-5 rel).
// Algebra: G = X X^T (symmetric tile-pairs, split-K partials, no atomics);
//          U = Wth G; z = (W2 f Wg + I) X + q 1^T, scaled by gamma in-epilogue;
//          zq = (W3 (P+I)) X + (W3 q + b3), stored pixel-major [B][N][D] for enc.
// Order: Deep-TEN chain first (zq->enc->bn->gamma), then z-GEMM fused with gamma.

typedef unsigned short u16;

#define Bb 8
#define Cc 512
#define C1 256
#define Dd 128
#define Kk 32
#define Nn 9216

typedef __attribute__((ext_vector_type(8))) short short8v;
typedef __attribute__((ext_vector_type(4))) short short4v;
typedef __attribute__((ext_vector_type(4))) float f32x4;

__device__ __forceinline__ float b2f(u16 u) {
  union { unsigned int i; float f; } v; v.i = ((unsigned int)u) << 16; return v.f;
}
__device__ __forceinline__ u16 f2b(float f) {
  union { float f; unsigned int i; } v; v.f = f;
  unsigned int x = v.i;
  return (u16)((x + 0x7fffu + ((x >> 16) & 1u)) >> 16);  // RNE
}

__device__ __forceinline__ float4 load4(const float* p) { return *(const float4*)p; }
__device__ __forceinline__ float4 load4(const u16* p) {
  ushort4 q = *(const ushort4*)p;
  return make_float4(b2f(q.x), b2f(q.y), b2f(q.z), b2f(q.w));
}
__device__ __forceinline__ void store4(float* p, float a, float b, float c, float d) {
  *(float4*)p = make_float4(a, b, c, d);
}

__device__ __forceinline__ float waveSum(float v) {
  #pragma unroll
  for (int o = 32; o > 0; o >>= 1) v += __shfl_xor(v, o);
  return v;
}
__device__ __forceinline__ float waveMax(float v) {
  #pragma unroll
  for (int o = 32; o > 0; o >>= 1) v = fmaxf(v, __shfl_xor(v, o));
  return v;
}
__device__ __forceinline__ float blockSum256(float v) {
  __shared__ float sm[4];
  v = waveSum(v);
  if ((threadIdx.x & 63) == 0) sm[threadIdx.x >> 6] = v;
  __syncthreads();
  float r = sm[0] + sm[1] + sm[2] + sm[3];
  __syncthreads();
  return r;
}
__device__ __forceinline__ float blockMax256(float v) {
  __shared__ float sm[4];
  v = waveMax(v);
  if ((threadIdx.x & 63) == 0) sm[threadIdx.x >> 6] = v;
  __syncthreads();
  float r = fmaxf(fmaxf(sm[0], sm[1]), fmaxf(sm[2], sm[3]));
  __syncthreads();
  return r;
}

// ---------------- MFMA split-bf16 common ----------------
__device__ __forceinline__ f32x4 mfma_bf16_16x16x32(short8v a, short8v b, f32x4 c) {
  asm("v_mfma_f32_16x16x32_bf16 %0, %1, %2, %0" : "+v"(c) : "v"(a), "v"(b));
  return c;
}

__device__ __forceinline__ int fsw(int r) { return (r ^ (r >> 2) ^ (r >> 4)) & 3; }

// 2 floats -> packed bf16 hi limbs (h) and lo limbs (l), 1 cvt_pk each + exact residual
__device__ __forceinline__ void cvt2(float x0, float x1, unsigned int& h, unsigned int& l) {
  asm("v_cvt_pk_bf16_f32 %0, %1, %2" : "=v"(h) : "v"(x0), "v"(x1));
  union { unsigned int u; float f; } fa, fb;
  fa.u = h << 16; fb.u = h & 0xffff0000u;
  float r0 = x0 - fa.f, r1 = x1 - fb.f;
  asm("v_cvt_pk_bf16_f32 %0, %1, %2" : "=v"(l) : "v"(r0), "v"(r1));
}

__device__ __forceinline__ void storeC4(float* p, float4 v) { *(float4*)p = v; }
__device__ __forceinline__ void storeC4(u16* p, float4 v) {
  ushort4 q; q.x = f2b(v.x); q.y = f2b(v.y); q.z = f2b(v.z); q.w = f2b(v.w);
  *(ushort4*)p = q;
}

// ---------------- generic MFMA GEMM ----------------
// C[b] = A[b] @ B[b]; fp32 in, TO out, 2-limb bf16 MFMA inside.
// BM = 128, BN = 32*NF, BK = 32. 256 threads = 4 waves (2x2), wave tile 64 x (16*NF).
// OMODE 0: row-major C[M][N], +biasRow[gr], *scaleRow[gr].
// OMODE 1: transposed C[N][128] (requires gny==1, M==128), +biasRow[d].
template<typename TO, int NF, int OMODE>
__global__ __launch_bounds__(256, 2) void gemm_mfma(
    const float* __restrict__ A, const float* __restrict__ B, TO* __restrict__ C,
    int N, int K,
    long long sA, long long sB, long long sC,
    const float* __restrict__ biasRow, long long sBias,
    const float* __restrict__ scaleRow,
    int gnx, int gny)
{
  static_assert(NF == 8, "NF");
  constexpr int BN = 32 * NF;
  // element (row,k) stored at column ((k>>3) ^ fsw(row))*8 + (k&7); stride 40 ushorts.
  __shared__ __align__(16) u16 Asm_[2][128][40];
  __shared__ __align__(16) u16 Bsm_[2][BN][40];

  int id = blockIdx.x;
  {
    const int nwg = gridDim.x;
    if ((nwg & 7) == 0) id = (id & 7) * (nwg >> 3) + (id >> 3);  // XCD chunk swizzle
  }
  const int per = gnx * gny;
  const int b = id / per;
  const int rem = id - b * per;
  const int by = rem % gny;        // m-block fastest
  const int bx = rem / gny;        // n-block
  A += b * sA; B += b * sB; C += b * sC;
  const int m0 = by * 128, n0 = bx * BN;

  const int t = threadIdx.x;
  const int w = t >> 6, lane = t & 63;
  const int wr = w >> 1, wc = w & 1;
  const int lr = lane & 15, lq = lane >> 4;

  const int sar = t >> 1, sak = (t & 1) * 16;   // A staging map
  const int kg = t >> 5, ng = t & 31;           // B staging map

  float ra[16];
  float rb[32];

  auto loadA = [&](int k0) {
    const float* p = A + (long long)(m0 + sar) * K + (k0 + sak);
    #pragma unroll
    for (int i = 0; i < 4; ++i) {
      float4 v = *(const float4*)(p + i * 4);
      ra[i*4+0] = v.x; ra[i*4+1] = v.y; ra[i*4+2] = v.z; ra[i*4+3] = v.w;
    }
  };
  auto loadB = [&](int k0) {
    const float* p = B + (long long)(k0 + kg * 4) * N + (n0 + ng * 8);
    #pragma unroll
    for (int i = 0; i < 4; ++i) {
      float4 v0 = *(const float4*)(p + (long long)i * N);
      float4 v1 = *(const float4*)(p + (long long)i * N + 4);
      rb[i*8+0]=v0.x; rb[i*8+1]=v0.y; rb[i*8+2]=v0.z; rb[i*8+3]=v0.w;
      rb[i*8+4]=v1.x; rb[i*8+5]=v1.y; rb[i*8+6]=v1.z; rb[i*8+7]=v1.w;
    }
  };

  auto stage = [&]() {
    {   // A rows sar, k-local sak..sak+15 -> two swizzled 8-blocks
      const int f = fsw(sar);
      #pragma unroll
      for (int h = 0; h < 2; ++h) {
        const int col = ((((sak >> 3) + h) ^ f) << 3);
        union { unsigned int u[4]; short8v v; } H, L;
        #pragma unroll
        for (int p = 0; p < 4; ++p) cvt2(ra[h*8+2*p], ra[h*8+2*p+1], H.u[p], L.u[p]);
        *(short8v*)&Asm_[0][sar][col] = H.v;
        *(short8v*)&Asm_[1][sar][col] = L.v;
      }
    }
    {   // transpose 4k x 8n block into n-major LDS, 4 consecutive k per b64 write
      #pragma unroll
      for (int j = 0; j < 8; ++j) {
        const int n = ng * 8 + j;
        const int col = (((kg >> 1) ^ fsw(n)) << 3) + (kg & 1) * 4;
        union { unsigned int u[2]; short4v v; } H, L;
        #pragma unroll
        for (int p = 0; p < 2; ++p)
          cvt2(rb[(2*p)*8 + j], rb[(2*p+1)*8 + j], H.u[p], L.u[p]);
        *(short4v*)&Bsm_[0][n][col] = H.v;
        *(short4v*)&Bsm_[1][n][col] = L.v;
      }
    }
  };

  f32x4 acc[4][NF];
  #pragma unroll
  for (int im = 0; im < 4; ++im)
    #pragma unroll
    for (int in = 0; in < NF; ++in)
      acc[im][in] = f32x4{0.f, 0.f, 0.f, 0.f};

  loadA(0); loadB(0);
  for (int k0 = 0; k0 < K; k0 += 32) {
    stage();
    if (k0 + 32 < K) { loadA(k0 + 32); loadB(k0 + 32); }
    __syncthreads();
    short8v af[2][4];
    #pragma unroll
    for (int im = 0; im < 4; ++im) {
      const int r = wr * 64 + im * 16 + lr;
      const int col = ((lq ^ fsw(r)) << 3);
      af[0][im] = *(const short8v*)&Asm_[0][r][col];
      af[1][im] = *(const short8v*)&Asm_[1][r][col];
    }
    #pragma unroll
    for (int in = 0; in < NF; ++in) {
      const int rB = wc * NF * 16 + in * 16 + lr;
      const int colB = ((lq ^ fsw(rB)) << 3);
      short8v bh = *(const short8v*)&Bsm_[0][rB][colB];
      short8v bl = *(const short8v*)&Bsm_[1][rB][colB];
      #pragma unroll
      for (int im = 0; im < 4; ++im) {
        acc[im][in] = mfma_bf16_16x16x32(af[0][im], bh, acc[im][in]);  // hi*hi
        acc[im][in] = mfma_bf16_16x16x32(af[0][im], bl, acc[im][in]);  // hi*lo
        acc[im][in] = mfma_bf16_16x16x32(af[1][im], bh, acc[im][in]);  // lo*hi
      }
    }
    __syncthreads();
  }
  asm volatile("s_nop 7\n\ts_nop 7\n\ts_nop 7");  // MFMA->VALU/VMEM read hazard guard

  if constexpr (OMODE == 1) {
    // transposed store: C[n][128]; d = wr*64+im*16+lq*4+{0..3} contiguous per lane
    const float* bb = biasRow + (long long)b * sBias;
    #pragma unroll
    for (int im = 0; im < 4; ++im) {
      #pragma unroll
      for (int in = 0; in < NF; ++in) {
        const f32x4 a = acc[im][in];
        const int gc = n0 + wc * NF * 16 + in * 16 + lr;
        const int d0b = wr * 64 + im * 16 + lq * 4;
        float4 v = make_float4(a[0] + bb[d0b + 0], a[1] + bb[d0b + 1],
                               a[2] + bb[d0b + 2], a[3] + bb[d0b + 3]);
        storeC4(&C[(long long)gc * Dd + d0b], v);
      }
    }
  } else {
    #pragma unroll
    for (int im = 0; im < 4; ++im) {
      #pragma unroll
      for (int in = 0; in < NF; ++in) {
        const f32x4 a = acc[im][in];
        const int gc = n0 + wc * NF * 16 + in * 16 + lr;   // C/D: col = lane&15
        #pragma unroll
        for (int p = 0; p < 4; ++p) {
          const int gr = m0 + wr * 64 + im * 16 + lq * 4 + p;  // row = (lane>>4)*4+reg
          float v = a[p];
          if (biasRow) v += biasRow[b * sBias + gr];
          if (scaleRow) v *= scaleRow[b * sBias + gr];
          C[(long long)gr * N + gc] = v;
        }
      }
    }
  }
}

// ---------------- G = X X^T, symmetric, split-K partials (no atomics) --------
__device__ __constant__ int PIa[10] = {0,0,0,0,1,1,1,2,2,3};
__device__ __constant__ int PJa[10] = {0,1,2,3,1,2,3,2,3,3};

__global__ __launch_bounds__(256, 2) void gxxt_kernel(
    const float* __restrict__ X, float* __restrict__ part,
    int numKS, int kChunk)
{
  __shared__ __align__(16) u16 Asm_[2][128][40];
  __shared__ __align__(16) u16 Bsm_[2][128][40];

  int id = blockIdx.x;
  {
    const int nwg = gridDim.x;
    if ((nwg & 7) == 0) id = (id & 7) * (nwg >> 3) + (id >> 3);  // one batch per XCD
  }
  const int pair = id % 10;
  const int rest = id / 10;
  const int ks = rest % numKS;
  const int b = rest / numKS;
  const int i0 = PIa[pair] * 128, j0 = PJa[pair] * 128;
  const bool same = (i0 == j0);
  const float* Xb = X + (long long)b * Cc * Nn;
  const int kBeg = ks * kChunk, kEnd = kBeg + kChunk;

  const int t = threadIdx.x;
  const int w = t >> 6, lane = t & 63;
  const int wr = w >> 1, wc = w & 1;
  const int lr = lane & 15, lq = lane >> 4;
  const int sar = t >> 1, sak = (t & 1) * 16;

  float ra[16], rb[16];

  auto loadA = [&](int k0) {
    const float* p = Xb + (long long)(i0 + sar) * Nn + (k0 + sak);
    #pragma unroll
    for (int i = 0; i < 4; ++i) {
      float4 v = *(const float4*)(p + i * 4);
      ra[i*4+0] = v.x; ra[i*4+1] = v.y; ra[i*4+2] = v.z; ra[i*4+3] = v.w;
    }
  };
  auto loadB = [&](int k0) {
    const float* p = Xb + (long long)(j0 + sar) * Nn + (k0 + sak);
    #pragma unroll
    for (int i = 0; i < 4; ++i) {
      float4 v = *(const float4*)(p + i * 4);
      rb[i*4+0] = v.x; rb[i*4+1] = v.y; rb[i*4+2] = v.z; rb[i*4+3] = v.w;
    }
  };
  auto stageRow = [&](const float* s16, u16 (*H)[40], u16 (*L)[40]) {
    const int f = fsw(sar);
    #pragma unroll
    for (int h = 0; h < 2; ++h) {
      const int col = ((((sak >> 3) + h) ^ f) << 3);
      union { unsigned int u[4]; short8v v; } Hv, Lv;
      #pragma unroll
      for (int p = 0; p < 4; ++p) cvt2(s16[h*8+2*p], s16[h*8+2*p+1], Hv.u[p], Lv.u[p]);
      *(short8v*)&H[sar][col] = Hv.v;
      *(short8v*)&L[sar][col] = Lv.v;
    }
  };

  const u16 (*BH)[40] = same ? Asm_[0] : Bsm_[0];
  const u16 (*BL)[40] = same ? Asm_[1] : Bsm_[1];

  f32x4 acc[4][4];
  #pragma unroll
  for (int im = 0; im < 4; ++im)
    #pragma unroll
    for (int in = 0; in < 4; ++in)
      acc[im][in] = f32x4{0.f, 0.f, 0.f, 0.f};

  loadA(kBeg);
  if (!same) loadB(kBeg);
  for (int k0 = kBeg; k0 < kEnd; k0 += 32) {
    stageRow(ra, Asm_[0], Asm_[1]);
    if (!same) stageRow(rb, Bsm_[0], Bsm_[1]);
    if (k0 + 32 < kEnd) { loadA(k0 + 32); if (!same) loadB(k0 + 32); }
    __syncthreads();
    short8v af[2][4];
    #pragma unroll
    for (int im = 0; im < 4; ++im) {
      const int r = wr * 64 + im * 16 + lr;
      const int col = ((lq ^ fsw(r)) << 3);
      af[0][im] = *(const short8v*)&Asm_[0][r][col];
      af[1][im] = *(const short8v*)&Asm_[1][r][col];
    }
    #pragma unroll
    for (int in = 0; in < 4; ++in) {
      const int rB = wc * 64 + in * 16 + lr;
      const int colB = ((lq ^ fsw(rB)) << 3);
      short8v bh = *(const short8v*)&BH[rB][colB];
      short8v bl = *(const short8v*)&BL[rB][colB];
      #pragma unroll
      for (int im = 0; im < 4; ++im) {
        acc[im][in] = mfma_bf16_16x16x32(af[0][im], bh, acc[im][in]);
        acc[im][in] = mfma_bf16_16x16x32(af[0][im], bl, acc[im][in]);
        acc[im][in] = mfma_bf16_16x16x32(af[1][im], bh, acc[im][in]);
      }
    }
    __syncthreads();
  }
  asm volatile("s_nop 7\n\ts_nop 7\n\ts_nop 7");

  float* Cp = part + ((long long)(ks * Bb + b) * 10 + pair) * 16384;
  #pragma unroll
  for (int im = 0; im < 4; ++im) {
    #pragma unroll
    for (int in = 0; in < 4; ++in) {
      const f32x4 a = acc[im][in];
      const int gc = wc * 64 + in * 16 + lr;
      #pragma unroll
      for (int p = 0; p < 4; ++p) {
        const int gr = wr * 64 + im * 16 + lq * 4 + p;
        Cp[gr * 128 + gc] = a[p];
      }
    }
  }
}

// Reduce partials -> G (both triangles). One block per (b, pair).
__global__ __launch_bounds__(256) void gred_kernel(const float* __restrict__ part,
    float* __restrict__ G, int numKS) {
  __shared__ float sm[64][129];
  const int pair = blockIdx.x % 10, b = blockIdx.x / 10;
  const int i0 = PIa[pair] * 128, j0 = PJa[pair] * 128;
  float* Gb = G + (long long)b * Cc * Cc;
  const long long ksStr = (long long)Bb * 10 * 16384;
  const float* p0 = part + ((long long)b * 10 + pair) * 16384;
  const int t = threadIdx.x;
  for (int half = 0; half < 2; ++half) {
    const int r0 = half * 64;
    __syncthreads();
    for (int rep = 0; rep < 32; ++rep) {
      int idx = r0 * 128 + rep * 256 + t;
      float s = 0.f;
      for (int ks = 0; ks < numKS; ++ks) s += p0[(long long)ks * ksStr + idx];
      int r = (idx >> 7) - r0, c = idx & 127;
      sm[r][c] = s;
      Gb[(long long)(i0 + r0 + r) * Cc + (j0 + c)] = s;
    }
    if (i0 != j0) {
      __syncthreads();
      for (int rep = 0; rep < 32; ++rep) {
        int o = rep * 256 + t;
        int rr = o >> 6, cc = o & 63;
        Gb[(long long)(j0 + rr) * Cc + (i0 + r0 + cc)] = sm[cc][rr];
      }
    }
  }
}

// ---------------- generic 64x64 tiled GEMM, fp32 (L only) ----------------
template<bool TRANSB>
__global__ __launch_bounds__(256) void gemm64(
    const float* __restrict__ A, const float* __restrict__ B, float* __restrict__ C,
    int M, int N, int K,
    long long sA, long long sB, long long sC,
    const float* __restrict__ biasRow, long long sBias)
{
  const int bz = blockIdx.z;
  A += (long long)bz * sA;
  B += (long long)bz * sB;
  C += (long long)bz * sC;
  const int m0 = blockIdx.y * 64, n0 = blockIdx.x * 64;
  __shared__ __align__(16) float As[16][64];
  __shared__ __align__(16) float Bs[16][64];
  const int t = threadIdx.x;
  const int lr = t >> 2, lk = (t & 3) << 2;
  const int tm = (t >> 4) << 2, tn = (t & 15) << 2;
  float acc[4][4] = {};
  for (int k0 = 0; k0 < K; k0 += 16) {
    {
      float4 a = load4(A + (long long)(m0 + lr) * K + (k0 + lk));
      As[lk + 0][lr] = a.x; As[lk + 1][lr] = a.y; As[lk + 2][lr] = a.z; As[lk + 3][lr] = a.w;
    }
    if (TRANSB) {
      float4 b = load4(B + (long long)(n0 + lr) * K + (k0 + lk));
      Bs[lk + 0][lr] = b.x; Bs[lk + 1][lr] = b.y; Bs[lk + 2][lr] = b.z; Bs[lk + 3][lr] = b.w;
    } else {
      const int kr = t >> 4, nc = (t & 15) << 2;
      float4 b = load4(B + (long long)(k0 + kr) * N + (n0 + nc));
      *(float4*)&Bs[kr][nc] = b;
    }
    __syncthreads();
    #pragma unroll
    for (int kk = 0; kk < 16; ++kk) {
      const float4 av = *(const float4*)&As[kk][tm];
      const float4 bv = *(const float4*)&Bs[kk][tn];
      acc[0][0] = fmaf(av.x, bv.x, acc[0][0]);
      acc[0][1] = fmaf(av.x, bv.y, acc[0][1]);
      acc[0][2] = fmaf(av.x, bv.z, acc[0][2]);
      acc[0][3] = fmaf(av.x, bv.w, acc[0][3]);
      acc[1][0] = fmaf(av.y, bv.x, acc[1][0]);
      acc[1][1] = fmaf(av.y, bv.y, acc[1][1]);
      acc[1][2] = fmaf(av.y, bv.z, acc[1][2]);
      acc[1][3] = fmaf(av.y, bv.w, acc[1][3]);
      acc[2][0] = fmaf(av.z, bv.x, acc[2][0]);
      acc[2][1] = fmaf(av.z, bv.y, acc[2][1]);
      acc[2][2] = fmaf(av.z, bv.z, acc[2][2]);
      acc[2][3] = fmaf(av.z, bv.w, acc[2][3]);
      acc[3][0] = fmaf(av.w, bv.x, acc[3][0]);
      acc[3][1] = fmaf(av.w, bv.y, acc[3][1]);
      acc[3][2] = fmaf(av.w, bv.z, acc[3][2]);
      acc[3][3] = fmaf(av.w, bv.w, acc[3][3]);
    }
    __syncthreads();
  }
  #pragma unroll
  for (int i = 0; i < 4; ++i) {
    const int m = m0 + tm + i;
    float bias = biasRow ? biasRow[bz * sBias + m] : 0.f;
    store4(C + (long long)m * N + (n0 + tn),
           acc[i][0] + bias, acc[i][1] + bias, acc[i][2] + bias, acc[i][3] + bias);
  }
}

// ---------------- small kernels ----------------
__global__ __launch_bounds__(256) void rowsum_kernel(const float* __restrict__ X,
                                                     float* __restrict__ s, int N) {
  long long row = blockIdx.x;
  const float* p = X + row * N;
  float acc = 0.f;
  for (int i = threadIdx.x; i < N; i += 256) acc += p[i];
  acc = blockSum256(acc);
  if (threadIdx.x == 0) s[row] = acc;
}

__global__ __launch_bounds__(256) void gemv512_kernel(const float* __restrict__ W,
                                                      const float* __restrict__ s,
                                                      float* __restrict__ out) {
  int b = blockIdx.x;
  __shared__ float ssm[Cc];
  for (int i = threadIdx.x; i < Cc; i += 256) ssm[i] = s[b * Cc + i];
  __syncthreads();
  int i = threadIdx.x;
  const float* wr = W + i * Cc;
  float acc = 0.f;
  for (int k = 0; k < Cc; ++k) acc = fmaf(wr[k], ssm[k], acc);
  out[b * C1 + i] = acc;
}

__global__ __launch_bounds__(256) void softmax_kernel(float* __restrict__ L,
    const float* __restrict__ bth, const float* __restrict__ bph,
    const float* __restrict__ u, const float* __restrict__ v) {
  int row = blockIdx.x;                 // b*256 + i
  int b = row >> 8, i = row & 255;
  int j = threadIdx.x;
  float bt = bth[i], bp = bph[j];
  long long idx = (long long)row * C1 + j;
  float val = L[idx] + bt * v[b * C1 + j] + u[b * C1 + i] * bp + (float)Nn * bt * bp;
  float mx = blockMax256(val);
  float p = expf(val - mx);
  float sm = blockSum256(p);
  L[idx] = p / sm;
}

__global__ __launch_bounds__(256) void w_kernel(const float* __restrict__ f,
                                                const float* __restrict__ bg,
                                                float* __restrict__ w) {
  int b = blockIdx.x;
  __shared__ float bgs[C1];
  bgs[threadIdx.x] = bg[threadIdx.x];
  __syncthreads();
  int i = threadIdx.x;
  const float* fr = f + ((long long)b * C1 + i) * C1;
  float acc = 0.f;
  for (int j = 0; j < C1; ++j) acc = fmaf(fr[j], bgs[j], acc);
  w[b * C1 + i] = acc;
}

__global__ __launch_bounds__(256) void q_kernel(const float* __restrict__ W2,
                                                const float* __restrict__ b2v,
                                                const float* __restrict__ w,
                                                float* __restrict__ q) {
  int gi = blockIdx.x * 256 + threadIdx.x;
  int b = gi >> 9, c = gi & 511;
  __shared__ float wsm[C1];
  wsm[threadIdx.x] = w[b * C1 + threadIdx.x];
  __syncthreads();
  const float* wr = W2 + c * C1;
  float acc = b2v[c];
  for (int i = 0; i < C1; ++i) acc = fmaf(wr[i], wsm[i], acc);
  q[gi] = acc;
}

// P[b] += I  (fold the residual connection into the GEMM operand)
__global__ __launch_bounds__(256) void adddiag_kernel(float* __restrict__ P) {
  int gi = blockIdx.x * 256 + threadIdx.x;   // [0, 8*512)
  int b = gi >> 9, c = gi & 511;
  P[((long long)b * Cc + c) * Cc + c] += 1.f;
}

// zqb[b][d] = b3[d] + sum_c W3[d][c] * q[b][c]
__global__ __launch_bounds__(256) void zqbias_kernel(const float* __restrict__ W3,
    const float* __restrict__ b3, const float* __restrict__ q, float* __restrict__ zqb) {
  int gi = blockIdx.x * 256 + threadIdx.x;   // [0, 1024)
  int b = gi >> 7, d = gi & 127;
  const float* wr = W3 + d * Cc;
  const float* qr = q + b * Cc;
  float acc = b3[d];
  for (int c = 0; c < Cc; ++c) acc = fmaf(wr[c], qr[c], acc);
  zqb[gi] = acc;
}

// Deep-TEN soft-assign + aggregation. zq is PIXEL-MAJOR [B][N][D].
template<typename ZT>
__global__ __launch_bounds__(256) void enc_kernel(
    const ZT* __restrict__ zq,      // [B][N][D]
    const float* __restrict__ cw,   // [K][D]
    const float* __restrict__ sc,   // [K]
    float* __restrict__ Eraw,       // [B][K][D] pre-zeroed
    float* __restrict__ Asum)       // [B][K]    pre-zeroed
{
  __shared__ float csm[Kk][Dd + 1];
  __shared__ float cc[Kk], ssm[Kk];
  __shared__ float sA[Kk][256 + 1];
  __shared__ float zs[16][Dd + 4];
  const int tid = threadIdx.x;
  const int b = blockIdx.y;
  const int n0 = blockIdx.x * 256;

  #pragma unroll
  for (int r = 0; r < 16; ++r) {
    int idx = r * 256 + tid;
    csm[idx >> 7][idx & 127] = cw[idx];
  }
  if (tid < Kk) ssm[tid] = sc[tid];
  __syncthreads();
  if (tid < Kk) {
    float a = 0.f;
    for (int d = 0; d < Dd; ++d) { float cv = csm[tid][d]; a = fmaf(cv, cv, a); }
    cc[tid] = a;
  }
  __syncthreads();

  // pass 1: one pixel per thread, contiguous row read
  const ZT* zrow = zq + ((long long)b * Nn + n0 + tid) * Dd;
  float dots[Kk];
  #pragma unroll
  for (int k = 0; k < Kk; ++k) dots[k] = 0.f;
  float xx = 0.f;
  for (int d = 0; d < Dd; d += 4) {
    float4 xv = load4(zrow + d);
    xx = fmaf(xv.x, xv.x, xx); xx = fmaf(xv.y, xv.y, xx);
    xx = fmaf(xv.z, xv.z, xx); xx = fmaf(xv.w, xv.w, xx);
    #pragma unroll
    for (int k = 0; k < Kk; ++k) {
      float dk = dots[k];
      dk = fmaf(csm[k][d + 0], xv.x, dk);
      dk = fmaf(csm[k][d + 1], xv.y, dk);
      dk = fmaf(csm[k][d + 2], xv.z, dk);
      dk = fmaf(csm[k][d + 3], xv.w, dk);
      dots[k] = dk;
    }
  }
  float mx = -1e30f;
  #pragma unroll
  for (int k = 0; k < Kk; ++k) {
    float l = ssm[k] * (xx - 2.f * dots[k] + cc[k]);
    dots[k] = l;
    mx = fmaxf(mx, l);
  }
  float sum = 0.f;
  #pragma unroll
  for (int k = 0; k < Kk; ++k) { float p = expf(dots[k] - mx); dots[k] = p; sum += p; }
  float inv = 1.f / sum;
  #pragma unroll
  for (int k = 0; k < Kk; ++k) sA[k][tid] = dots[k] * inv;
  __syncthreads();
  if (tid < Kk) {
    float s = 0.f;
    for (int p = 0; p < 256; ++p) s += sA[tid][p];
    atomicAdd(&Asum[b * Kk + tid], s);
  }

  // pass 2: E_part[k][d0..d0+15] over this tile's 256 pixels (16 px per stage)
  float acc[16];
  #pragma unroll
  for (int j = 0; j < 16; ++j) acc[j] = 0.f;
  const int k = tid & 31, d0 = (tid >> 5) * 16;
  const int spx = tid >> 4, sd = (tid & 15) * 8;   // staging: 16 px x 128 d, coalesced
  for (int it = 0; it < 16; ++it) {
    __syncthreads();
    {
      const ZT* src = zq + ((long long)b * Nn + n0 + it * 16 + spx) * Dd + sd;
      float4 a4 = load4(src);
      float4 b4 = load4(src + 4);
      *(float4*)&zs[spx][sd] = a4;
      *(float4*)&zs[spx][sd + 4] = b4;
    }
    __syncthreads();
    #pragma unroll
    for (int p = 0; p < 16; ++p) {
      float a = sA[k][it * 16 + p];
      #pragma unroll
      for (int j = 0; j < 16; ++j) acc[j] = fmaf(a, zs[p][d0 + j], acc[j]);
    }
  }
  float* Ep = Eraw + ((long long)b * Kk + k) * Dd + d0;
  #pragma unroll
  for (int j = 0; j < 16; ++j) atomicAdd(Ep + j, acc[j]);
}

__global__ __launch_bounds__(256) void bn_kernel(const float* __restrict__ Eraw,
    const float* __restrict__ Asum, const float* __restrict__ cw, float* __restrict__ Es) {
  int k = blockIdx.x, tid = threadIdx.x;
  float vals[4], s = 0.f, s2 = 0.f;
  #pragma unroll
  for (int r = 0; r < 4; ++r) {
    int i = r * 256 + tid;
    int b = i >> 7, d = i & 127;
    float e = Eraw[((long long)b * Kk + k) * Dd + d] - Asum[b * Kk + k] * cw[k * Dd + d];
    vals[r] = e; s += e; s2 = fmaf(e, e, s2);
  }
  s = blockSum256(s);
  s2 = blockSum256(s2);
  float mean = s * (1.f / 1024.f);
  float var = fmaxf(s2 * (1.f / 1024.f) - mean * mean, 0.f);
  float rs = rsqrtf(var + 1e-5f);
  #pragma unroll
  for (int r = 0; r < 4; ++r) {
    int i = r * 256 + tid;
    int b = i >> 7, d = i & 127;
    float e = (vals[r] - mean) * rs;
    if (e > 0.f) atomicAdd(&Es[b * Dd + d], e);
  }
}

__global__ __launch_bounds__(256) void gamma_kernel(const float* __restrict__ Es,
    const float* __restrict__ Wfc, const float* __restrict__ bfc, float* __restrict__ gam) {
  int gi = blockIdx.x * 256 + threadIdx.x;
  int b = gi >> 9, c = gi & 511;
  __shared__ float esm[Dd];
  if (threadIdx.x < Dd) esm[threadIdx.x] = Es[b * Dd + threadIdx.x];
  __syncthreads();
  const float* wr = Wfc + c * Dd;
  float acc = bfc[c];
  for (int d = 0; d < Dd; ++d) acc = fmaf(wr[d], esm[d], acc);
  gam[gi] = 1.f / (1.f + expf(-acc));
}

// ---------------- host launcher ----------------
extern "C" void kernel_launch(void* const* d_in, const int* in_sizes, int n_in,
                              void* d_out, int out_size, void* d_ws, size_t ws_size,
                              hipStream_t stream) {
  const float* X   = (const float*)d_in[0];
  const float* Wth = (const float*)d_in[1];
  const float* bth = (const float*)d_in[2];
  const float* Wph = (const float*)d_in[3];
  const float* bph = (const float*)d_in[4];
  const float* Wg  = (const float*)d_in[5];
  const float* bg  = (const float*)d_in[6];
  const float* W2  = (const float*)d_in[7];
  const float* b2v = (const float*)d_in[8];
  const float* W3  = (const float*)d_in[9];
  const float* b3v = (const float*)d_in[10];
  const float* CW  = (const float*)d_in[11];
  const float* SC  = (const float*)d_in[12];
  const float* Wfc = (const float*)d_in[13];
  const float* bfc = (const float*)d_in[14];
  float* out = (float*)d_out;
  float* wsf = (float*)d_ws;

  const long long szL   = (long long)Bb * C1 * C1;   // 524288
  const long long szRA  = (long long)Bb * Cc * Cc;   // 2097152
  const long long szRB  = (long long)Bb * C1 * Cc;   // 1048576
  long long off = 0;
  float* s_   = wsf + off; off += Bb * Cc;
  float* u_   = wsf + off; off += Bb * C1;
  float* v_   = wsf + off; off += Bb * C1;
  float* w_   = wsf + off; off += Bb * C1;
  float* q_   = wsf + off; off += Bb * Cc;
  float* Eraw_= wsf + off; off += (long long)Bb * Kk * Dd;
  float* Es_  = wsf + off; off += Bb * Dd;
  float* Asum_= wsf + off; off += Bb * Kk;
  float* gam_ = wsf + off; off += Bb * Cc;
  float* L_   = wsf + off; off += szL;
  float* regA = wsf + off; off += szRA;
  float* regB = wsf + off; off += szRB;
  const long long baseFloats = off;
  // tail region: G split-K partials, later aliased by zq (pixel-major [B][N][D])
  float* tail = wsf + off;
  const long long ZQ_F  = (long long)Bb * Dd * Nn;      // 9437184
  const long long tailFloats = (long long)(ws_size / 4) - baseFloats;
  const bool big = tailFloats >= ZQ_F;    // big: fp32 zq + splitK=6; small: bf16 zq + splitK=2
  const int numKS = big ? 6 : 2;          // partials: numKS*8*10*16384 floats (7.9M / 2.6M)
  float* part = tail;
  float* zqf  = tail;
  u16*   zqh  = (u16*)tail;
  float* R_   = L_;    // alias: f dead after Mm-GEMM; R born after P-GEMM
  float* zqb_ = u_;    // alias: u dead after softmax

  const long long strX = (long long)Cc * Nn;
  const long long sG = (long long)Cc * Cc;
  const long long sU = (long long)C1 * Cc;
  const long long sL = (long long)C1 * C1;
  const long long sR = (long long)Dd * Cc;

  rowsum_kernel<<<Bb * Cc, 256, 0, stream>>>(X, s_, Nn);
  // G = X X^T (symmetric): tile-pair partials -> reduce into regA
  gxxt_kernel<<<dim3(10 * numKS * Bb), 256, 0, stream>>>(X, part, numKS, Nn / numKS);
  gred_kernel<<<dim3(10 * Bb), 256, 0, stream>>>(part, regA, numKS);
  // U = Wth @ G -> regB  (MFMA, M=256 N=512 K=512)
  gemm_mfma<float, 8, 0><<<dim3(32), 256, 0, stream>>>(
      Wth, regA, regB, Cc, Cc, 0, sG, sU, nullptr, 0, nullptr, 2, 2);
  gemv512_kernel<<<Bb, 256, 0, stream>>>(Wth, s_, u_);
  gemv512_kernel<<<Bb, 256, 0, stream>>>(Wph, s_, v_);
  // L = U @ Wph^T  (small, fp32)
  gemm64<true><<<dim3(4, 4, Bb), 256, 0, stream>>>(
      regB, Wph, L_, C1, C1, Cc, sU, 0, sL, nullptr, 0);
  softmax_kernel<<<Bb * C1, 256, 0, stream>>>(L_, bth, bph, u_, v_);
  w_kernel<<<Bb, 256, 0, stream>>>(L_, bg, w_);
  // Mm = f @ Wg -> regB (U dead)  (MFMA, M=256 N=512 K=256)
  gemm_mfma<float, 8, 0><<<dim3(32), 256, 0, stream>>>(
      L_, Wg, regB, Cc, C1, sL, 0, sU, nullptr, 0, nullptr, 2, 2);
  q_kernel<<<16, 256, 0, stream>>>(W2, b2v, w_, q_);
  // P = W2 @ Mm -> regA (G dead)  (MFMA, M=512 N=512 K=256) ; then P += I
  gemm_mfma<float, 8, 0><<<dim3(64), 256, 0, stream>>>(
      W2, regB, regA, Cc, C1, 0, sU, sG, nullptr, 0, nullptr, 2, 4);
  adddiag_kernel<<<16, 256, 0, stream>>>(regA);
  // R = W3 @ P' -> R_ (alias L_)  (MFMA, M=128 N=512 K=512) ; zq bias = W3 q + b3
  gemm_mfma<float, 8, 0><<<dim3(16), 256, 0, stream>>>(
      W3, regA, R_, Cc, Cc, 0, sG, sR, nullptr, 0, nullptr, 2, 1);
  zqbias_kernel<<<4, 256, 0, stream>>>(W3, b3v, q_, zqb_);
  hipMemsetAsync(Eraw_, 0, (size_t)(Bb * Kk * Dd + Bb * Dd + Bb * Kk) * 4, stream);
  // zq = R @ X + zqb, stored pixel-major [B][N][D]  (partials dead -> tail reused)
  if (big) {
    gemm_mfma<float, 8, 1><<<dim3(288), 256, 0, stream>>>(
        R_, X, zqf, Nn, Cc, sR, strX, (long long)Dd * Nn, zqb_, Dd, nullptr, 36, 1);
    enc_kernel<float><<<dim3(36, Bb), 256, 0, stream>>>(zqf, CW, SC, Eraw_, Asum_);
  } else {
    gemm_mfma<u16, 8, 1><<<dim3(288), 256, 0, stream>>>(
        R_, X, zqh, Nn, Cc, sR, strX, (long long)Dd * Nn, zqb_, Dd, nullptr, 36, 1);
    enc_kernel<u16><<<dim3(36, Bb), 256, 0, stream>>>(zqh, CW, SC, Eraw_, Asum_);
  }
  bn_kernel<<<Kk, 256, 0, stream>>>(Eraw_, Asum_, CW, Es_);
  gamma_kernel<<<16, 256, 0, stream>>>(Es_, Wfc, bfc, gam_);
  // z*gamma = (P' @ X + q) * gamma  -> out  (gamma fused in epilogue; no scaleout pass)
  gemm_mfma<float, 8, 0><<<dim3(1152), 256, 0, stream>>>(
      regA, X, out, Nn, Cc, sG, strX, strX, q_, Cc, gam_, 36, 4);
  (void)in_sizes; (void)n_in; (void)out_size;
}

// Round 6
// 1039.446 us; speedup vs baseline: 1.8669x; 1.0543x over previous
//
#include <hip/hip_runtime.h>

// NLCE: non-local (channel attention) + Deep-TEN encoding, B=8 C=512 C1=256 D=128 K=32 N=9216.
// All inputs/outputs fp32. Big GEMMs on matrix cores via 2-limb bf16 split
// (hi/lo via v_cvt_pk_bf16_f32; products hi*hi+hi*lo+lo*hi, ~1e-5 rel).
// Algebra: G = X X^T (symmetric tile-pairs, split-K partials, no atomics);
//          U = Wth G; P' = W2 f Wg + I (I fused in epilogue);
//          zq = (W3 P') X + (W3 q + b3) pixel-major; gamma from Deep-TEN chain;
//          z*gamma = (diag(gamma) P') X + gamma*q  (gamma folded into operand+bias).

typedef unsigned short u16;

#define Bb 8
#define Cc 512
#define C1 256
#define Dd 128
#define Kk 32
#define Nn 9216

typedef __attribute__((ext_vector_type(8))) short short8v;
typedef __attribute__((ext_vector_type(4))) short short4v;
typedef __attribute__((ext_vector_type(4))) float f32x4;

__device__ __forceinline__ float b2f(u16 u) {
  union { unsigned int i; float f; } v; v.i = ((unsigned int)u) << 16; return v.f;
}
__device__ __forceinline__ u16 f2b(float f) {
  union { float f; unsigned int i; } v; v.f = f;
  unsigned int x = v.i;
  return (u16)((x + 0x7fffu + ((x >> 16) & 1u)) >> 16);  // RNE
}

__device__ __forceinline__ float4 load4(const float* p) { return *(const float4*)p; }
__device__ __forceinline__ float4 load4(const u16* p) {
  ushort4 q = *(const ushort4*)p;
  return make_float4(b2f(q.x), b2f(q.y), b2f(q.z), b2f(q.w));
}
__device__ __forceinline__ void store4(float* p, float a, float b, float c, float d) {
  *(float4*)p = make_float4(a, b, c, d);
}

__device__ __forceinline__ float waveSum(float v) {
  #pragma unroll
  for (int o = 32; o > 0; o >>= 1) v += __shfl_xor(v, o);
  return v;
}
__device__ __forceinline__ float waveMax(float v) {
  #pragma unroll
  for (int o = 32; o > 0; o >>= 1) v = fmaxf(v, __shfl_xor(v, o));
  return v;
}
__device__ __forceinline__ float blockSum256(float v) {
  __shared__ float sm[4];
  v = waveSum(v);
  if ((threadIdx.x & 63) == 0) sm[threadIdx.x >> 6] = v;
  __syncthreads();
  float r = sm[0] + sm[1] + sm[2] + sm[3];
  __syncthreads();
  return r;
}
__device__ __forceinline__ float blockMax256(float v) {
  __shared__ float sm[4];
  v = waveMax(v);
  if ((threadIdx.x & 63) == 0) sm[threadIdx.x >> 6] = v;
  __syncthreads();
  float r = fmaxf(fmaxf(sm[0], sm[1]), fmaxf(sm[2], sm[3]));
  __syncthreads();
  return r;
}

// ---------------- MFMA split-bf16 common ----------------
__device__ __forceinline__ f32x4 mfma_bf16_16x16x32(short8v a, short8v b, f32x4 c) {
  asm("v_mfma_f32_16x16x32_bf16 %0, %1, %2, %0" : "+v"(c) : "v"(a), "v"(b));
  return c;
}

__device__ __forceinline__ int fsw(int r) { return (r ^ (r >> 2) ^ (r >> 4)) & 3; }

// 2 floats -> packed bf16 hi limbs (h) and lo limbs (l), 1 cvt_pk each + exact residual
__device__ __forceinline__ void cvt2(float x0, float x1, unsigned int& h, unsigned int& l) {
  asm("v_cvt_pk_bf16_f32 %0, %1, %2" : "=v"(h) : "v"(x0), "v"(x1));
  union { unsigned int u; float f; } fa, fb;
  fa.u = h << 16; fb.u = h & 0xffff0000u;
  float r0 = x0 - fa.f, r1 = x1 - fb.f;
  asm("v_cvt_pk_bf16_f32 %0, %1, %2" : "=v"(l) : "v"(r0), "v"(r1));
}

__device__ __forceinline__ void storeC4(float* p, float4 v) { *(float4*)p = v; }
__device__ __forceinline__ void storeC4(u16* p, float4 v) {
  ushort4 q; q.x = f2b(v.x); q.y = f2b(v.y); q.z = f2b(v.z); q.w = f2b(v.w);
  *(ushort4*)p = q;
}

// ---------------- generic MFMA GEMM ----------------
// C[b] = A[b] @ B[b]; fp32 in, TO out, 2-limb bf16 MFMA inside.
// BM = 128, BN = 32*NF, BK = 32. 256 threads = 4 waves (2x2), wave tile 64 x (16*NF).
// OMODE 0: row-major C[M][N], +biasRow[gr]; ADDI adds identity (gr==gc).
// OMODE 1: transposed C[N][128] (requires gny==1, M==128), +biasRow[d].
template<typename TO, int NF, int OMODE, bool ADDI>
__global__ __launch_bounds__(256, 2) void gemm_mfma(
    const float* __restrict__ A, const float* __restrict__ B, TO* __restrict__ C,
    int N, int K,
    long long sA, long long sB, long long sC,
    const float* __restrict__ biasRow, long long sBias,
    int gnx, int gny)
{
  static_assert(NF == 8, "NF");
  constexpr int BN = 32 * NF;
  // element (row,k) stored at column ((k>>3) ^ fsw(row))*8 + (k&7); stride 40 ushorts.
  __shared__ __align__(16) u16 Asm_[2][128][40];
  __shared__ __align__(16) u16 Bsm_[2][BN][40];

  int id = blockIdx.x;
  {
    const int nwg = gridDim.x;
    if ((nwg & 7) == 0) id = (id & 7) * (nwg >> 3) + (id >> 3);  // XCD chunk swizzle
  }
  const int per = gnx * gny;
  const int b = id / per;
  const int rem = id - b * per;
  const int by = rem % gny;        // m-block fastest
  const int bx = rem / gny;        // n-block
  A += b * sA; B += b * sB; C += b * sC;
  const int m0 = by * 128, n0 = bx * BN;

  const int t = threadIdx.x;
  const int w = t >> 6, lane = t & 63;
  const int wr = w >> 1, wc = w & 1;
  const int lr = lane & 15, lq = lane >> 4;

  const int sar = t >> 1, sak = (t & 1) * 16;   // A staging map
  const int kg = t >> 5, ng = t & 31;           // B staging map

  float ra[16];
  float rb[32];

  auto loadA = [&](int k0) {
    const float* p = A + (long long)(m0 + sar) * K + (k0 + sak);
    #pragma unroll
    for (int i = 0; i < 4; ++i) {
      float4 v = *(const float4*)(p + i * 4);
      ra[i*4+0] = v.x; ra[i*4+1] = v.y; ra[i*4+2] = v.z; ra[i*4+3] = v.w;
    }
  };
  auto loadB = [&](int k0) {
    const float* p = B + (long long)(k0 + kg * 4) * N + (n0 + ng * 8);
    #pragma unroll
    for (int i = 0; i < 4; ++i) {
      float4 v0 = *(const float4*)(p + (long long)i * N);
      float4 v1 = *(const float4*)(p + (long long)i * N + 4);
      rb[i*8+0]=v0.x; rb[i*8+1]=v0.y; rb[i*8+2]=v0.z; rb[i*8+3]=v0.w;
      rb[i*8+4]=v1.x; rb[i*8+5]=v1.y; rb[i*8+6]=v1.z; rb[i*8+7]=v1.w;
    }
  };

  auto stage = [&]() {
    {   // A rows sar, k-local sak..sak+15 -> two swizzled 8-blocks
      const int f = fsw(sar);
      #pragma unroll
      for (int h = 0; h < 2; ++h) {
        const int col = ((((sak >> 3) + h) ^ f) << 3);
        union { unsigned int u[4]; short8v v; } H, L;
        #pragma unroll
        for (int p = 0; p < 4; ++p) cvt2(ra[h*8+2*p], ra[h*8+2*p+1], H.u[p], L.u[p]);
        *(short8v*)&Asm_[0][sar][col] = H.v;
        *(short8v*)&Asm_[1][sar][col] = L.v;
      }
    }
    {   // transpose 4k x 8n block into n-major LDS, 4 consecutive k per b64 write
      #pragma unroll
      for (int j = 0; j < 8; ++j) {
        const int n = ng * 8 + j;
        const int col = (((kg >> 1) ^ fsw(n)) << 3) + (kg & 1) * 4;
        union { unsigned int u[2]; short4v v; } H, L;
        #pragma unroll
        for (int p = 0; p < 2; ++p)
          cvt2(rb[(2*p)*8 + j], rb[(2*p+1)*8 + j], H.u[p], L.u[p]);
        *(short4v*)&Bsm_[0][n][col] = H.v;
        *(short4v*)&Bsm_[1][n][col] = L.v;
      }
    }
  };

  f32x4 acc[4][NF];
  #pragma unroll
  for (int im = 0; im < 4; ++im)
    #pragma unroll
    for (int in = 0; in < NF; ++in)
      acc[im][in] = f32x4{0.f, 0.f, 0.f, 0.f};

  loadA(0); loadB(0);
  for (int k0 = 0; k0 < K; k0 += 32) {
    stage();
    if (k0 + 32 < K) { loadA(k0 + 32); loadB(k0 + 32); }
    __syncthreads();
    short8v af[2][4];
    #pragma unroll
    for (int im = 0; im < 4; ++im) {
      const int r = wr * 64 + im * 16 + lr;
      const int col = ((lq ^ fsw(r)) << 3);
      af[0][im] = *(const short8v*)&Asm_[0][r][col];
      af[1][im] = *(const short8v*)&Asm_[1][r][col];
    }
    #pragma unroll
    for (int in = 0; in < NF; ++in) {
      const int rB = wc * NF * 16 + in * 16 + lr;
      const int colB = ((lq ^ fsw(rB)) << 3);
      short8v bh = *(const short8v*)&Bsm_[0][rB][colB];
      short8v bl = *(const short8v*)&Bsm_[1][rB][colB];
      #pragma unroll
      for (int im = 0; im < 4; ++im) {
        acc[im][in] = mfma_bf16_16x16x32(af[0][im], bh, acc[im][in]);  // hi*hi
        acc[im][in] = mfma_bf16_16x16x32(af[0][im], bl, acc[im][in]);  // hi*lo
        acc[im][in] = mfma_bf16_16x16x32(af[1][im], bh, acc[im][in]);  // lo*hi
      }
    }
    __syncthreads();
  }
  asm volatile("s_nop 7\n\ts_nop 7\n\ts_nop 7");  // MFMA->VALU/VMEM read hazard guard

  if constexpr (OMODE == 1) {
    // transposed store: C[n][128]; d = wr*64+im*16+lq*4+{0..3} contiguous per lane
    const float* bb = biasRow + (long long)b * sBias;
    #pragma unroll
    for (int im = 0; im < 4; ++im) {
      #pragma unroll
      for (int in = 0; in < NF; ++in) {
        const f32x4 a = acc[im][in];
        const int gc = n0 + wc * NF * 16 + in * 16 + lr;
        const int d0b = wr * 64 + im * 16 + lq * 4;
        float4 v = make_float4(a[0] + bb[d0b + 0], a[1] + bb[d0b + 1],
                               a[2] + bb[d0b + 2], a[3] + bb[d0b + 3]);
        storeC4(&C[(long long)gc * Dd + d0b], v);
      }
    }
  } else {
    #pragma unroll
    for (int im = 0; im < 4; ++im) {
      #pragma unroll
      for (int in = 0; in < NF; ++in) {
        const f32x4 a = acc[im][in];
        const int gc = n0 + wc * NF * 16 + in * 16 + lr;   // C/D: col = lane&15
        #pragma unroll
        for (int p = 0; p < 4; ++p) {
          const int gr = m0 + wr * 64 + im * 16 + lq * 4 + p;  // row = (lane>>4)*4+reg
          float v = a[p];
          if (biasRow) v += biasRow[b * sBias + gr];
          if (ADDI && gr == gc) v += 1.f;
          C[(long long)gr * N + gc] = v;
        }
      }
    }
  }
}

// ---------------- G = X X^T, symmetric, split-K partials (no atomics) --------
__device__ __constant__ int PIa[10] = {0,0,0,0,1,1,1,2,2,3};
__device__ __constant__ int PJa[10] = {0,1,2,3,1,2,3,2,3,3};

__global__ __launch_bounds__(256, 2) void gxxt_kernel(
    const float* __restrict__ X, float* __restrict__ part,
    int numKS, int kChunk)
{
  __shared__ __align__(16) u16 Asm_[2][128][40];
  __shared__ __align__(16) u16 Bsm_[2][128][40];

  int id = blockIdx.x;
  {
    const int nwg = gridDim.x;
    if ((nwg & 7) == 0) id = (id & 7) * (nwg >> 3) + (id >> 3);  // one batch per XCD
  }
  const int pair = id % 10;
  const int rest = id / 10;
  const int ks = rest % numKS;
  const int b = rest / numKS;
  const int i0 = PIa[pair] * 128, j0 = PJa[pair] * 128;
  const bool same = (i0 == j0);
  const float* Xb = X + (long long)b * Cc * Nn;
  const int kBeg = ks * kChunk, kEnd = kBeg + kChunk;

  const int t = threadIdx.x;
  const int w = t >> 6, lane = t & 63;
  const int wr = w >> 1, wc = w & 1;
  const int lr = lane & 15, lq = lane >> 4;
  const int sar = t >> 1, sak = (t & 1) * 16;

  float ra[16], rb[16];

  auto loadA = [&](int k0) {
    const float* p = Xb + (long long)(i0 + sar) * Nn + (k0 + sak);
    #pragma unroll
    for (int i = 0; i < 4; ++i) {
      float4 v = *(const float4*)(p + i * 4);
      ra[i*4+0] = v.x; ra[i*4+1] = v.y; ra[i*4+2] = v.z; ra[i*4+3] = v.w;
    }
  };
  auto loadB = [&](int k0) {
    const float* p = Xb + (long long)(j0 + sar) * Nn + (k0 + sak);
    #pragma unroll
    for (int i = 0; i < 4; ++i) {
      float4 v = *(const float4*)(p + i * 4);
      rb[i*4+0] = v.x; rb[i*4+1] = v.y; rb[i*4+2] = v.z; rb[i*4+3] = v.w;
    }
  };
  auto stageRow = [&](const float* s16, u16 (*H)[40], u16 (*L)[40]) {
    const int f = fsw(sar);
    #pragma unroll
    for (int h = 0; h < 2; ++h) {
      const int col = ((((sak >> 3) + h) ^ f) << 3);
      union { unsigned int u[4]; short8v v; } Hv, Lv;
      #pragma unroll
      for (int p = 0; p < 4; ++p) cvt2(s16[h*8+2*p], s16[h*8+2*p+1], Hv.u[p], Lv.u[p]);
      *(short8v*)&H[sar][col] = Hv.v;
      *(short8v*)&L[sar][col] = Lv.v;
    }
  };

  const u16 (*BH)[40] = same ? Asm_[0] : Bsm_[0];
  const u16 (*BL)[40] = same ? Asm_[1] : Bsm_[1];

  f32x4 acc[4][4];
  #pragma unroll
  for (int im = 0; im < 4; ++im)
    #pragma unroll
    for (int in = 0; in < 4; ++in)
      acc[im][in] = f32x4{0.f, 0.f, 0.f, 0.f};

  loadA(kBeg);
  if (!same) loadB(kBeg);
  for (int k0 = kBeg; k0 < kEnd; k0 += 32) {
    stageRow(ra, Asm_[0], Asm_[1]);
    if (!same) stageRow(rb, Bsm_[0], Bsm_[1]);
    if (k0 + 32 < kEnd) { loadA(k0 + 32); if (!same) loadB(k0 + 32); }
    __syncthreads();
    short8v af[2][4];
    #pragma unroll
    for (int im = 0; im < 4; ++im) {
      const int r = wr * 64 + im * 16 + lr;
      const int col = ((lq ^ fsw(r)) << 3);
      af[0][im] = *(const short8v*)&Asm_[0][r][col];
      af[1][im] = *(const short8v*)&Asm_[1][r][col];
    }
    #pragma unroll
    for (int in = 0; in < 4; ++in) {
      const int rB = wc * 64 + in * 16 + lr;
      const int colB = ((lq ^ fsw(rB)) << 3);
      short8v bh = *(const short8v*)&BH[rB][colB];
      short8v bl = *(const short8v*)&BL[rB][colB];
      #pragma unroll
      for (int im = 0; im < 4; ++im) {
        acc[im][in] = mfma_bf16_16x16x32(af[0][im], bh, acc[im][in]);
        acc[im][in] = mfma_bf16_16x16x32(af[0][im], bl, acc[im][in]);
        acc[im][in] = mfma_bf16_16x16x32(af[1][im], bh, acc[im][in]);
      }
    }
    __syncthreads();
  }
  asm volatile("s_nop 7\n\ts_nop 7\n\ts_nop 7");

  float* Cp = part + ((long long)(ks * Bb + b) * 10 + pair) * 16384;
  #pragma unroll
  for (int im = 0; im < 4; ++im) {
    #pragma unroll
    for (int in = 0; in < 4; ++in) {
      const f32x4 a = acc[im][in];
      const int gc = wc * 64 + in * 16 + lr;
      #pragma unroll
      for (int p = 0; p < 4; ++p) {
        const int gr = wr * 64 + im * 16 + lq * 4 + p;
        Cp[gr * 128 + gc] = a[p];
      }
    }
  }
}

// Reduce partials -> G (both triangles). One block per (b, pair).
__global__ __launch_bounds__(256) void gred_kernel(const float* __restrict__ part,
    float* __restrict__ G, int numKS) {
  __shared__ float sm[64][129];
  const int pair = blockIdx.x % 10, b = blockIdx.x / 10;
  const int i0 = PIa[pair] * 128, j0 = PJa[pair] * 128;
  float* Gb = G + (long long)b * Cc * Cc;
  const long long ksStr = (long long)Bb * 10 * 16384;
  const float* p0 = part + ((long long)b * 10 + pair) * 16384;
  const int t = threadIdx.x;
  for (int half = 0; half < 2; ++half) {
    const int r0 = half * 64;
    __syncthreads();
    for (int rep = 0; rep < 32; ++rep) {
      int idx = r0 * 128 + rep * 256 + t;
      float s = 0.f;
      for (int ks = 0; ks < numKS; ++ks) s += p0[(long long)ks * ksStr + idx];
      int r = (idx >> 7) - r0, c = idx & 127;
      sm[r][c] = s;
      Gb[(long long)(i0 + r0 + r) * Cc + (j0 + c)] = s;
    }
    if (i0 != j0) {
      __syncthreads();
      for (int rep = 0; rep < 32; ++rep) {
        int o = rep * 256 + t;
        int rr = o >> 6, cc = o & 63;
        Gb[(long long)(j0 + rr) * Cc + (i0 + r0 + cc)] = sm[cc][rr];
      }
    }
  }
}

// ---------------- generic 64x64 tiled GEMM, fp32 (L only) ----------------
template<bool TRANSB>
__global__ __launch_bounds__(256) void gemm64(
    const float* __restrict__ A, const float* __restrict__ B, float* __restrict__ C,
    int M, int N, int K,
    long long sA, long long sB, long long sC,
    const float* __restrict__ biasRow, long long sBias)
{
  const int bz = blockIdx.z;
  A += (long long)bz * sA;
  B += (long long)bz * sB;
  C += (long long)bz * sC;
  const int m0 = blockIdx.y * 64, n0 = blockIdx.x * 64;
  __shared__ __align__(16) float As[16][64];
  __shared__ __align__(16) float Bs[16][64];
  const int t = threadIdx.x;
  const int lr = t >> 2, lk = (t & 3) << 2;
  const int tm = (t >> 4) << 2, tn = (t & 15) << 2;
  float acc[4][4] = {};
  for (int k0 = 0; k0 < K; k0 += 16) {
    {
      float4 a = load4(A + (long long)(m0 + lr) * K + (k0 + lk));
      As[lk + 0][lr] = a.x; As[lk + 1][lr] = a.y; As[lk + 2][lr] = a.z; As[lk + 3][lr] = a.w;
    }
    if (TRANSB) {
      float4 b = load4(B + (long long)(n0 + lr) * K + (k0 + lk));
      Bs[lk + 0][lr] = b.x; Bs[lk + 1][lr] = b.y; Bs[lk + 2][lr] = b.z; Bs[lk + 3][lr] = b.w;
    } else {
      const int kr = t >> 4, nc = (t & 15) << 2;
      float4 b = load4(B + (long long)(k0 + kr) * N + (n0 + nc));
      *(float4*)&Bs[kr][nc] = b;
    }
    __syncthreads();
    #pragma unroll
    for (int kk = 0; kk < 16; ++kk) {
      const float4 av = *(const float4*)&As[kk][tm];
      const float4 bv = *(const float4*)&Bs[kk][tn];
      acc[0][0] = fmaf(av.x, bv.x, acc[0][0]);
      acc[0][1] = fmaf(av.x, bv.y, acc[0][1]);
      acc[0][2] = fmaf(av.x, bv.z, acc[0][2]);
      acc[0][3] = fmaf(av.x, bv.w, acc[0][3]);
      acc[1][0] = fmaf(av.y, bv.x, acc[1][0]);
      acc[1][1] = fmaf(av.y, bv.y, acc[1][1]);
      acc[1][2] = fmaf(av.y, bv.z, acc[1][2]);
      acc[1][3] = fmaf(av.y, bv.w, acc[1][3]);
      acc[2][0] = fmaf(av.z, bv.x, acc[2][0]);
      acc[2][1] = fmaf(av.z, bv.y, acc[2][1]);
      acc[2][2] = fmaf(av.z, bv.z, acc[2][2]);
      acc[2][3] = fmaf(av.z, bv.w, acc[2][3]);
      acc[3][0] = fmaf(av.w, bv.x, acc[3][0]);
      acc[3][1] = fmaf(av.w, bv.y, acc[3][1]);
      acc[3][2] = fmaf(av.w, bv.z, acc[3][2]);
      acc[3][3] = fmaf(av.w, bv.w, acc[3][3]);
    }
    __syncthreads();
  }
  #pragma unroll
  for (int i = 0; i < 4; ++i) {
    const int m = m0 + tm + i;
    float bias = biasRow ? biasRow[bz * sBias + m] : 0.f;
    store4(C + (long long)m * N + (n0 + tn),
           acc[i][0] + bias, acc[i][1] + bias, acc[i][2] + bias, acc[i][3] + bias);
  }
}

// ---------------- small kernels ----------------
__global__ __launch_bounds__(256) void rowsum_kernel(const float* __restrict__ X,
                                                     float* __restrict__ s, int N) {
  long long row = blockIdx.x;
  const float* p = X + row * N;
  float acc = 0.f;
  for (int i = threadIdx.x; i < N; i += 256) acc += p[i];
  acc = blockSum256(acc);
  if (threadIdx.x == 0) s[row] = acc;
}

// u[b,i] = sum Wth[i,:]*s[b,:]  (sel 0), v[b,i] = sum Wph[i,:]*s[b,:] (sel 1)
__global__ __launch_bounds__(256) void gemv2_kernel(const float* __restrict__ Wth,
    const float* __restrict__ Wph, const float* __restrict__ s,
    float* __restrict__ u, float* __restrict__ v) {
  int b = blockIdx.x & 7, sel = blockIdx.x >> 3;
  const float* W = sel ? Wph : Wth;
  float* out = sel ? v : u;
  __shared__ float ssm[Cc];
  for (int i = threadIdx.x; i < Cc; i += 256) ssm[i] = s[b * Cc + i];
  __syncthreads();
  int i = threadIdx.x;
  const float* wr = W + i * Cc;
  float acc = 0.f;
  for (int k = 0; k < Cc; ++k) acc = fmaf(wr[k], ssm[k], acc);
  out[b * C1 + i] = acc;
}

// softmax over rows of L with bias terms; also emits w[b,i] = sum_j f * bg[j]
__global__ __launch_bounds__(256) void softmax_kernel(float* __restrict__ L,
    const float* __restrict__ bth, const float* __restrict__ bph,
    const float* __restrict__ u, const float* __restrict__ v,
    const float* __restrict__ bg, float* __restrict__ w) {
  __shared__ float bgs[C1];
  int row = blockIdx.x;                 // b*256 + i
  int b = row >> 8, i = row & 255;
  int j = threadIdx.x;
  bgs[j] = bg[j];
  float bt = bth[i], bp = bph[j];
  long long idx = (long long)row * C1 + j;
  float val = L[idx] + bt * v[b * C1 + j] + u[b * C1 + i] * bp + (float)Nn * bt * bp;
  float mx = blockMax256(val);
  float p = expf(val - mx);
  float sm = blockSum256(p);
  float f = p / sm;
  L[idx] = f;
  float ws = blockSum256(f * bgs[j]);
  if (j == 0) w[row] = ws;
}

__global__ __launch_bounds__(256) void q_kernel(const float* __restrict__ W2,
                                                const float* __restrict__ b2v,
                                                const float* __restrict__ w,
                                                float* __restrict__ q) {
  int gi = blockIdx.x * 256 + threadIdx.x;
  int b = gi >> 9, c = gi & 511;
  __shared__ float wsm[C1];
  wsm[threadIdx.x] = w[b * C1 + threadIdx.x];
  __syncthreads();
  const float* wr = W2 + c * C1;
  float acc = b2v[c];
  for (int i = 0; i < C1; ++i) acc = fmaf(wr[i], wsm[i], acc);
  q[gi] = acc;
}

// zqb[b][d] = b3[d] + sum_c W3[d][c] * q[b][c]
__global__ __launch_bounds__(256) void zqbias_kernel(const float* __restrict__ W3,
    const float* __restrict__ b3, const float* __restrict__ q, float* __restrict__ zqb) {
  int gi = blockIdx.x * 256 + threadIdx.x;   // [0, 1024)
  int b = gi >> 7, d = gi & 127;
  const float* wr = W3 + d * Cc;
  const float* qr = q + b * Cc;
  float acc = b3[d];
  for (int c = 0; c < Cc; ++c) acc = fmaf(wr[c], qr[c], acc);
  zqb[gi] = acc;
}

// Deep-TEN soft-assign + aggregation. zq is PIXEL-MAJOR [B][N][D].
// Eraw8/Asum8: 8-slot replicated accumulators (slot = n-tile & 7) to cut atomic contention.
template<typename ZT>
__global__ __launch_bounds__(256) void enc_kernel(
    const ZT* __restrict__ zq,      // [B][N][D]
    const float* __restrict__ cw,   // [K][D]
    const float* __restrict__ sc,   // [K]
    float* __restrict__ Eraw8,      // [8][B][K][D] pre-zeroed
    float* __restrict__ Asum8)      // [8][B][K]    pre-zeroed
{
  __shared__ float csm[Kk][Dd + 1];
  __shared__ float cc[Kk], ssm[Kk];
  __shared__ float sA[Kk][256 + 1];
  __shared__ float zs[16][Dd + 4];
  const int tid = threadIdx.x;
  const int b = blockIdx.y;
  const int slot = blockIdx.x & 7;
  const int n0 = blockIdx.x * 256;

  #pragma unroll
  for (int r = 0; r < 16; ++r) {
    int idx = r * 256 + tid;
    csm[idx >> 7][idx & 127] = cw[idx];
  }
  if (tid < Kk) ssm[tid] = sc[tid];
  __syncthreads();
  if (tid < Kk) {
    float a = 0.f;
    for (int d = 0; d < Dd; ++d) { float cv = csm[tid][d]; a = fmaf(cv, cv, a); }
    cc[tid] = a;
  }
  __syncthreads();

  // pass 1: one pixel per thread, contiguous row read
  const ZT* zrow = zq + ((long long)b * Nn + n0 + tid) * Dd;
  float dots[Kk];
  #pragma unroll
  for (int k = 0; k < Kk; ++k) dots[k] = 0.f;
  float xx = 0.f;
  for (int d = 0; d < Dd; d += 4) {
    float4 xv = load4(zrow + d);
    xx = fmaf(xv.x, xv.x, xx); xx = fmaf(xv.y, xv.y, xx);
    xx = fmaf(xv.z, xv.z, xx); xx = fmaf(xv.w, xv.w, xx);
    #pragma unroll
    for (int k = 0; k < Kk; ++k) {
      float dk = dots[k];
      dk = fmaf(csm[k][d + 0], xv.x, dk);
      dk = fmaf(csm[k][d + 1], xv.y, dk);
      dk = fmaf(csm[k][d + 2], xv.z, dk);
      dk = fmaf(csm[k][d + 3], xv.w, dk);
      dots[k] = dk;
    }
  }
  float mx = -1e30f;
  #pragma unroll
  for (int k = 0; k < Kk; ++k) {
    float l = ssm[k] * (xx - 2.f * dots[k] + cc[k]);
    dots[k] = l;
    mx = fmaxf(mx, l);
  }
  float sum = 0.f;
  #pragma unroll
  for (int k = 0; k < Kk; ++k) { float p = expf(dots[k] - mx); dots[k] = p; sum += p; }
  float inv = 1.f / sum;
  #pragma unroll
  for (int k = 0; k < Kk; ++k) sA[k][tid] = dots[k] * inv;
  __syncthreads();
  if (tid < Kk) {
    float s = 0.f;
    for (int p = 0; p < 256; ++p) s += sA[tid][p];
    atomicAdd(&Asum8[((long long)slot * Bb + b) * Kk + tid], s);
  }

  // pass 2: E_part[k][d0..d0+15] over this tile's 256 pixels (16 px per stage)
  float acc[16];
  #pragma unroll
  for (int j = 0; j < 16; ++j) acc[j] = 0.f;
  const int k = tid & 31, d0 = (tid >> 5) * 16;
  const int spx = tid >> 4, sd = (tid & 15) * 8;   // staging: 16 px x 128 d, coalesced
  for (int it = 0; it < 16; ++it) {
    __syncthreads();
    {
      const ZT* src = zq + ((long long)b * Nn + n0 + it * 16 + spx) * Dd + sd;
      float4 a4 = load4(src);
      float4 b4 = load4(src + 4);
      *(float4*)&zs[spx][sd] = a4;
      *(float4*)&zs[spx][sd + 4] = b4;
    }
    __syncthreads();
    #pragma unroll
    for (int p = 0; p < 16; ++p) {
      float a = sA[k][it * 16 + p];
      #pragma unroll
      for (int j = 0; j < 16; ++j) acc[j] = fmaf(a, zs[p][d0 + j], acc[j]);
    }
  }
  float* Ep = Eraw8 + (((long long)slot * Bb + b) * Kk + k) * Dd + d0;
  #pragma unroll
  for (int j = 0; j < 16; ++j) atomicAdd(Ep + j, acc[j]);
}

// per-k BN over (b,d) with 8-slot reduction, relu, Es[b,d] += e
__global__ __launch_bounds__(256) void bn_kernel(const float* __restrict__ Eraw8,
    const float* __restrict__ Asum8, const float* __restrict__ cw, float* __restrict__ Es) {
  __shared__ float sas[8];
  int k = blockIdx.x, tid = threadIdx.x;
  if (tid < 8) {
    float a = 0.f;
    for (int sl = 0; sl < 8; ++sl) a += Asum8[((long long)sl * Bb + tid) * Kk + k];
    sas[tid] = a;
  }
  __syncthreads();
  float vals[4], s = 0.f, s2 = 0.f;
  #pragma unroll
  for (int r = 0; r < 4; ++r) {
    int i = r * 256 + tid;
    int b = i >> 7, d = i & 127;
    float e = 0.f;
    for (int sl = 0; sl < 8; ++sl)
      e += Eraw8[(((long long)sl * Bb + b) * Kk + k) * Dd + d];
    e -= sas[b] * cw[k * Dd + d];
    vals[r] = e; s += e; s2 = fmaf(e, e, s2);
  }
  s = blockSum256(s);
  s2 = blockSum256(s2);
  float mean = s * (1.f / 1024.f);
  float var = fmaxf(s2 * (1.f / 1024.f) - mean * mean, 0.f);
  float rs = rsqrtf(var + 1e-5f);
  #pragma unroll
  for (int r = 0; r < 4; ++r) {
    int i = r * 256 + tid;
    int b = i >> 7, d = i & 127;
    float e = (vals[r] - mean) * rs;
    if (e > 0.f) atomicAdd(&Es[b * Dd + d], e);
  }
}

// gamma = sigmoid(Es @ Wfc^T + bfc); also folds gamma into q (q <- q*gamma)
__global__ __launch_bounds__(256) void gamma_kernel(const float* __restrict__ Es,
    const float* __restrict__ Wfc, const float* __restrict__ bfc,
    float* __restrict__ gam, float* __restrict__ q) {
  int gi = blockIdx.x * 256 + threadIdx.x;
  int b = gi >> 9, c = gi & 511;
  __shared__ float esm[Dd];
  if (threadIdx.x < Dd) esm[threadIdx.x] = Es[b * Dd + threadIdx.x];
  __syncthreads();
  const float* wr = Wfc + c * Dd;
  float acc = bfc[c];
  for (int d = 0; d < Dd; ++d) acc = fmaf(wr[d], esm[d], acc);
  float g = 1.f / (1.f + expf(-acc));
  gam[gi] = g;
  q[gi] *= g;
}

// P[b][c][:] *= gam[b][c]  (fold output scale into the GEMM A-operand)
__global__ __launch_bounds__(256) void scaleP_kernel(float* __restrict__ P,
    const float* __restrict__ gam) {
  long long f = ((long long)blockIdx.x * 256 + threadIdx.x) * 4;  // 8*512*512 total
  int b = (int)(f >> 18), c = (int)((f >> 9) & 511);
  float g = gam[b * Cc + c];
  float4 v = *(const float4*)(P + f);
  store4(P + f, v.x * g, v.y * g, v.z * g, v.w * g);
}

// ---------------- host launcher ----------------
extern "C" void kernel_launch(void* const* d_in, const int* in_sizes, int n_in,
                              void* d_out, int out_size, void* d_ws, size_t ws_size,
                              hipStream_t stream) {
  const float* X   = (const float*)d_in[0];
  const float* Wth = (const float*)d_in[1];
  const float* bth = (const float*)d_in[2];
  const float* Wph = (const float*)d_in[3];
  const float* bph = (const float*)d_in[4];
  const float* Wg  = (const float*)d_in[5];
  const float* bg  = (const float*)d_in[6];
  const float* W2  = (const float*)d_in[7];
  const float* b2v = (const float*)d_in[8];
  const float* W3  = (const float*)d_in[9];
  const float* b3v = (const float*)d_in[10];
  const float* CW  = (const float*)d_in[11];
  const float* SC  = (const float*)d_in[12];
  const float* Wfc = (const float*)d_in[13];
  const float* bfc = (const float*)d_in[14];
  float* out = (float*)d_out;
  float* wsf = (float*)d_ws;

  const long long szL   = (long long)Bb * C1 * C1;   // 524288
  const long long szRA  = (long long)Bb * Cc * Cc;   // 2097152
  const long long szRB  = (long long)Bb * C1 * Cc;   // 1048576
  long long off = 0;
  float* s_   = wsf + off; off += Bb * Cc;
  float* u_   = wsf + off; off += Bb * C1;
  float* v_   = wsf + off; off += Bb * C1;
  float* w_   = wsf + off; off += Bb * C1;
  float* q_   = wsf + off; off += Bb * Cc;
  float* Eraw_= wsf + off; off += (long long)Bb * Kk * Dd;   // legacy slot (unused)
  float* Es_  = wsf + off; off += Bb * Dd;
  float* Asum_= wsf + off; off += Bb * Kk;                   // legacy slot (unused)
  float* gam_ = wsf + off; off += Bb * Cc;
  float* L_   = wsf + off; off += szL;
  float* regA = wsf + off; off += szRA;
  float* regB = wsf + off; off += szRB;
  const long long baseFloats = off;
  // tail region: G split-K partials, later aliased by zq (pixel-major [B][N][D])
  float* tail = wsf + off;
  const long long ZQ_F  = (long long)Bb * Dd * Nn;      // 9437184
  const long long tailFloats = (long long)(ws_size / 4) - baseFloats;
  const bool big = tailFloats >= ZQ_F;    // big: fp32 zq + splitK=6; small: bf16 zq + splitK=2
  const int numKS = big ? 6 : 2;          // partials: numKS*8*10*16384 floats (7.9M / 2.6M)
  float* part = tail;
  float* zqf  = tail;
  u16*   zqh  = (u16*)tail;
  float* R_   = L_;     // alias: f dead after Mm-GEMM; R born after P-GEMM
  float* zqb_ = u_;     // alias: u dead after softmax
  float* E8_  = regB;                       // 8*8*32*128 = 262144 floats (regB dead post-P)
  float* A8_  = regB + 262144;              // 8*8*32 = 2048 floats
  (void)Eraw_; (void)Asum_;

  const long long strX = (long long)Cc * Nn;
  const long long sG = (long long)Cc * Cc;
  const long long sU = (long long)C1 * Cc;
  const long long sL = (long long)C1 * C1;
  const long long sR = (long long)Dd * Cc;

  rowsum_kernel<<<Bb * Cc, 256, 0, stream>>>(X, s_, Nn);
  // G = X X^T (symmetric): tile-pair partials -> reduce into regA
  gxxt_kernel<<<dim3(10 * numKS * Bb), 256, 0, stream>>>(X, part, numKS, Nn / numKS);
  gred_kernel<<<dim3(10 * Bb), 256, 0, stream>>>(part, regA, numKS);
  // U = Wth @ G -> regB  (MFMA, M=256 N=512 K=512)
  gemm_mfma<float, 8, 0, false><<<dim3(32), 256, 0, stream>>>(
      Wth, regA, regB, Cc, Cc, 0, sG, sU, nullptr, 0, 2, 2);
  gemv2_kernel<<<16, 256, 0, stream>>>(Wth, Wph, s_, u_, v_);
  // L = U @ Wph^T  (small, fp32)
  gemm64<true><<<dim3(4, 4, Bb), 256, 0, stream>>>(
      regB, Wph, L_, C1, C1, Cc, sU, 0, sL, nullptr, 0);
  softmax_kernel<<<Bb * C1, 256, 0, stream>>>(L_, bth, bph, u_, v_, bg, w_);
  // Mm = f @ Wg -> regB (U dead)  (MFMA, M=256 N=512 K=256)
  gemm_mfma<float, 8, 0, false><<<dim3(32), 256, 0, stream>>>(
      L_, Wg, regB, Cc, C1, sL, 0, sU, nullptr, 0, 2, 2);
  q_kernel<<<16, 256, 0, stream>>>(W2, b2v, w_, q_);
  // P' = W2 @ Mm + I -> regA (G dead; identity fused in epilogue)
  gemm_mfma<float, 8, 0, true><<<dim3(64), 256, 0, stream>>>(
      W2, regB, regA, Cc, C1, 0, sU, sG, nullptr, 0, 2, 4);
  // regB dead: becomes 8-slot enc accumulators
  hipMemsetAsync(regB, 0, (size_t)(262144 + 2048) * 4, stream);
  hipMemsetAsync(Es_, 0, (size_t)(Bb * Dd) * 4, stream);
  // R = W3 @ P' -> R_ (alias L_)  (MFMA, M=128 N=512 K=512) ; zq bias = W3 q + b3
  gemm_mfma<float, 8, 0, false><<<dim3(16), 256, 0, stream>>>(
      W3, regA, R_, Cc, Cc, 0, sG, sR, nullptr, 0, 2, 1);
  zqbias_kernel<<<4, 256, 0, stream>>>(W3, b3v, q_, zqb_);
  // zq = R @ X + zqb, stored pixel-major [B][N][D]  (partials dead -> tail reused)
  if (big) {
    gemm_mfma<float, 8, 1, false><<<dim3(288), 256, 0, stream>>>(
        R_, X, zqf, Nn, Cc, sR, strX, (long long)Dd * Nn, zqb_, Dd, 36, 1);
    enc_kernel<float><<<dim3(36, Bb), 256, 0, stream>>>(zqf, CW, SC, E8_, A8_);
  } else {
    gemm_mfma<u16, 8, 1, false><<<dim3(288), 256, 0, stream>>>(
        R_, X, zqh, Nn, Cc, sR, strX, (long long)Dd * Nn, zqb_, Dd, 36, 1);
    enc_kernel<u16><<<dim3(36, Bb), 256, 0, stream>>>(zqh, CW, SC, E8_, A8_);
  }
  bn_kernel<<<Kk, 256, 0, stream>>>(E8_, A8_, CW, Es_);
  gamma_kernel<<<16, 256, 0, stream>>>(Es_, Wfc, bfc, gam_, q_);   // q <- q*gamma
  // fold gamma into P' rows, then z*gamma = (gamma.P') @ X + (gamma.q) -> out
  scaleP_kernel<<<2048, 256, 0, stream>>>(regA, gam_);
  gemm_mfma<float, 8, 0, false><<<dim3(1152), 256, 0, stream>>>(
      regA, X, out, Nn, Cc, sG, strX, strX, q_, Cc, 36, 4);
  (void)in_sizes; (void)n_in; (void)out_size;
}